// Round 17
// baseline (810.243 us; speedup 1.0000x reference)
//
#include <hip/hip_runtime.h>
#include <cstddef>
#include <cstdint>
#include <cmath>

#define D_MODEL 2048
#define DICT    32768
#define KTOP    32
#define NCAND_FB 96         // fallback hist margin (rank cum >= 96)
#define CAPMAX  256
#define T_OPT   2.70f       // epilogue collect threshold
#define BKT     32                  // K-tile depth (r17: halved -> 64KB LDS)
#define NT_K    (D_MODEL / BKT)     // 64 K-tiles
#define NROWS   2048
#define TMB     (NROWS / 256)       // 8  row tiles
#define TNB     (DICT / 256)        // 128 col tiles

typedef float    f32x4  __attribute__((ext_vector_type(4)));
typedef __bf16   bf16x8 __attribute__((ext_vector_type(8)));
typedef unsigned short us8 __attribute__((ext_vector_type(8)));

__device__ __forceinline__ unsigned short f2bf_rne(float f) {
    unsigned u = __builtin_bit_cast(unsigned, f);
    unsigned r = u + 0x7fffu + ((u >> 16) & 1u);
    return (unsigned short)(r >> 16);
}

__device__ __forceinline__ void gload16(const void* g, const void* s) {
    __builtin_amdgcn_global_load_lds(
        (const __attribute__((address_space(1))) unsigned int*)g,
        (__attribute__((address_space(3))) unsigned int*)s, 16, 0, 0);
}

// ---------------------------------------------------------------------------
// Convert x and We f32 -> bf16, pre-tiled per 256-row tile into 64 K-tiles of
// 32 k. Per (tile,ktile): [half(row>=128) 8KB][rloc 0..127][64B row], with
// byte ^= ((rloc&7)<<4) baked in (bijective: linear triangular map on bits
// 4..8; GEMM ds_read uses the identical formula).
// ---------------------------------------------------------------------------
__global__ __launch_bounds__(256) void convert_tiles(
    const float* __restrict__ x,
    const float* __restrict__ We,
    unsigned short* __restrict__ xbf,     // [TMB][NT_K][8192] ushorts
    unsigned short* __restrict__ webf)    // [TNB][NT_K][8192] ushorts
{
    const size_t NX = (size_t)NROWS * 64;
    size_t id = (size_t)blockIdx.x * 256 + threadIdx.x;

    const float* src;
    unsigned short* dstb;
    int row, s;
    if (id < NX) {
        row = (int)(id >> 6); s = (int)(id & 63);
        src = x + (size_t)row * D_MODEL + s * 32;
        dstb = xbf + ((size_t)(row >> 8) * NT_K + s) * 8192
                   + ((row >> 7) & 1) * 4096;
    } else {
        id -= NX;
        row = (int)(id >> 6); s = (int)(id & 63);
        src = We + (size_t)row * D_MODEL + s * 32;
        dstb = webf + ((size_t)(row >> 8) * NT_K + s) * 8192
                    + ((row >> 7) & 1) * 4096;
    }
    const int rloc = row & 127;

    #pragma unroll
    for (int qc = 0; qc < 4; ++qc) {
        float4 v0 = reinterpret_cast<const float4*>(src)[qc * 2];
        float4 v1 = reinterpret_cast<const float4*>(src)[qc * 2 + 1];
        us8 c;
        c[0] = f2bf_rne(v0.x); c[1] = f2bf_rne(v0.y);
        c[2] = f2bf_rne(v0.z); c[3] = f2bf_rne(v0.w);
        c[4] = f2bf_rne(v1.x); c[5] = f2bf_rne(v1.y);
        c[6] = f2bf_rne(v1.z); c[7] = f2bf_rne(v1.w);
        const int byteoff = (rloc * 64 + qc * 16) ^ ((rloc & 7) << 4);
        *reinterpret_cast<us8*>(reinterpret_cast<char*>(dstb) + byteoff) = c;
    }
}

// ---------------------------------------------------------------------------
// Encoder GEMM r17: 256x256 tile, BK=32, LDS 64KB -> 2 BLOCKS/CU. The r16
// structure was strictly serial (reads-drain then MFMA, sum not max: 7030
// cyc/K-tile vs 2800 ideal) with no second wave-set to fill the bubbles.
// Two independent blocks per CU drift out of phase: one drains ds_reads
// while the other issues MFMA (m114 mechanism). 2 phases per K-tile:
// P1{12 reads; bar; lgkm0; 16 MFMA; bar} P2{stage 4 half-tiles(u+2);
// vmcnt(4); bar; 16 MFMA; bar}. Ledger: vmcnt(4) retires tile u+1 exactly;
// stages overwrite [cur] whose reads drained at P1's lgkmcnt(0).
// ---------------------------------------------------------------------------
__global__ __launch_bounds__(512, 2) void encoder_bf16(
    const unsigned short* __restrict__ xbf,
    const unsigned short* __restrict__ webf,
    const float* __restrict__ bias,
    float* __restrict__ C,
    int* __restrict__ cand_idx,           // [NROWS][cap]
    int* __restrict__ cand_cnt,           // [NROWS], pre-zeroed
    int cap)
{
    __shared__ __align__(16) unsigned short Ab[2][2][4096];   // [dbuf][half] 8KB
    __shared__ __align__(16) unsigned short Bb[2][2][4096];

    const int t    = threadIdx.x;
    const int lane = t & 63;
    const int w    = t >> 6;        // 0..7
    const int wm   = w >> 2;        // 0..1  (128-row half = A half)
    const int wn   = w & 3;         // 0..3  (64-col slice)
    const int hB   = wn >> 1;       // B half index

    const int bid = blockIdx.x;
    const int swz = (bid & 7) * (TMB * TNB / 8) + (bid >> 3);
    const int mt  = swz & (TMB - 1);
    const int nt  = swz >> 3;

    const char* As = (const char*)xbf  + (size_t)mt * (NT_K * 16384);
    const char* Bs = (const char*)webf + (size_t)nt * (NT_K * 16384);

    f32x4 acc[8][4];
    #pragma unroll
    for (int i = 0; i < 8; ++i)
        #pragma unroll
        for (int j = 0; j < 4; ++j) acc[i][j] = (f32x4)0.f;

    const int soff = t * 16;        // byte offset in 8KB half-tile
    const int dsti = t * 8;         // ushort idx in LDS half-buf

    #define STAGE_A(buf, u, h) \
        gload16(As + (size_t)(u) * 16384 + (h) * 8192 + soff, &Ab[buf][h][dsti])
    #define STAGE_B(buf, u, h) \
        gload16(Bs + (size_t)(u) * 16384 + (h) * 8192 + soff, &Bb[buf][h][dsti])

    bf16x8 a[8], b[4];
    const int q16 = (lane >> 4) * 16;

    #define LDA_ALL() do {                                                   \
        _Pragma("unroll") for (int i = 0; i < 8; ++i) {                      \
            const int rl = i * 16 + (lane & 15);                             \
            const int by = (rl * 64 + q16) ^ ((rl & 7) << 4);                \
            a[i] = __builtin_bit_cast(bf16x8,                                \
                *reinterpret_cast<const us8*>(                               \
                    (const char*)&Ab[cur][wm][0] + by));                     \
        } } while (0)
    #define LDB_ALL() do {                                                   \
        _Pragma("unroll") for (int j = 0; j < 4; ++j) {                      \
            const int cl = (wn & 1) * 64 + j * 16 + (lane & 15);             \
            const int by = (cl * 64 + q16) ^ ((cl & 7) << 4);                \
            b[j] = __builtin_bit_cast(bf16x8,                                \
                *reinterpret_cast<const us8*>(                               \
                    (const char*)&Bb[cur][hB][0] + by));                     \
        } } while (0)
    #define MMA_HALF(ib) do {                                                \
        _Pragma("unroll") for (int i = 0; i < 4; ++i)                        \
        _Pragma("unroll") for (int j = 0; j < 4; ++j)                        \
            acc[(ib) + i][j] = __builtin_amdgcn_mfma_f32_16x16x32_bf16(      \
                a[(ib) + i], b[j], acc[(ib) + i][j], 0, 0, 0);               \
    } while (0)

    // prologue: stage tiles 0 and 1 (8 loads/thread); retire tile 0
    STAGE_B(0, 0, 0); STAGE_B(0, 0, 1);
    STAGE_A(0, 0, 0); STAGE_A(0, 0, 1);
    STAGE_B(1, 1, 0); STAGE_B(1, 1, 1);
    STAGE_A(1, 1, 0); STAGE_A(1, 1, 1);
    asm volatile("s_waitcnt vmcnt(4)" ::: "memory");
    __builtin_amdgcn_sched_barrier(0);
    __builtin_amdgcn_s_barrier();

    int cur = 0;
    for (int u = 0; u < NT_K; ++u) {
        // ---- P1: all 12 frag reads; MFMA rows 0-3
        LDA_ALL();
        LDB_ALL();
        __builtin_amdgcn_s_barrier();
        asm volatile("s_waitcnt lgkmcnt(0)" ::: "memory");
        __builtin_amdgcn_sched_barrier(0);
        __builtin_amdgcn_s_setprio(1);
        MMA_HALF(0);
        __builtin_amdgcn_s_setprio(0);
        __builtin_amdgcn_s_barrier();

        // ---- P2: stage tile u+2 into [cur]; counted vmcnt; MFMA rows 4-7
        if (u + 2 < NT_K) {
            STAGE_B(cur, u + 2, 0); STAGE_B(cur, u + 2, 1);
            STAGE_A(cur, u + 2, 0); STAGE_A(cur, u + 2, 1);
            asm volatile("s_waitcnt vmcnt(4)" ::: "memory");
        } else {
            asm volatile("s_waitcnt vmcnt(0)" ::: "memory");
        }
        __builtin_amdgcn_sched_barrier(0);
        __builtin_amdgcn_s_barrier();
        __builtin_amdgcn_s_setprio(1);
        MMA_HALF(4);
        __builtin_amdgcn_s_setprio(0);
        __builtin_amdgcn_s_barrier();

        cur ^= 1;
    }
    #undef STAGE_A
    #undef STAGE_B
    #undef LDA_ALL
    #undef LDB_ALL
    #undef MMA_HALF

    const int m0 = mt * 256, n0 = nt * 256;
    float bvj[4];
    #pragma unroll
    for (int j = 0; j < 4; ++j)
        bvj[j] = bias[n0 + wn * 64 + j * 16 + (lane & 15)];

    // pure store loop (no branches/atomics)
    #pragma unroll
    for (int j = 0; j < 4; ++j) {
        const int col = n0 + wn * 64 + j * 16 + (lane & 15);
        #pragma unroll
        for (int i = 0; i < 8; ++i) {
            const int rowb = m0 + wm * 128 + i * 16 + ((lane >> 4) * 4);
            #pragma unroll
            for (int r = 0; r < 4; ++r)
                C[(size_t)(rowb + r) * DICT + col] = acc[i][j][r] + bvj[j];
        }
    }

    // collection: thread-local 4-slot compare pass, then short emission.
    int nh = 0, h0 = 0, h1 = 0, h2 = 0, h3 = 0;
    #pragma unroll
    for (int j = 0; j < 4; ++j) {
        const int col = n0 + wn * 64 + j * 16 + (lane & 15);
        #pragma unroll
        for (int i = 0; i < 8; ++i) {
            const int rowb = m0 + wm * 128 + i * 16 + ((lane >> 4) * 4);
            #pragma unroll
            for (int r = 0; r < 4; ++r) {
                if (acc[i][j][r] + bvj[j] >= T_OPT) {
                    const int enc = ((rowb + r) << 15) | col;
                    if      (nh == 0) h0 = enc;
                    else if (nh == 1) h1 = enc;
                    else if (nh == 2) h2 = enc;
                    else if (nh == 3) h3 = enc;
                    else {
                        const int row2 = enc >> 15;
                        const int pos2 = atomicAdd(&cand_cnt[row2], 1);
                        if (pos2 < cap)
                            cand_idx[(size_t)row2 * cap + pos2] = enc & 0x7FFF;
                    }
                    ++nh;
                }
            }
        }
    }
    #pragma unroll
    for (int s2 = 0; s2 < 4; ++s2) {
        if (nh > s2) {
            const int enc = (s2 == 0) ? h0 : (s2 == 1) ? h1
                          : (s2 == 2) ? h2 : h3;
            const int row2 = enc >> 15;
            const int pos  = atomicAdd(&cand_cnt[row2], 1);
            if (pos < cap)
                cand_idx[(size_t)row2 * cap + pos] = enc & 0x7FFF;
        }
    }
}

// ---------------------------------------------------------------------------
// Exact f32 recompute + features-row zeroing + exact top-32 + scatter.
// Three approx bands: skip / sure-in (use approx) / ambiguous (exact dot).
// Fallback hist path for degenerate rows (correctness never depends on T_OPT).
// ---------------------------------------------------------------------------
__global__ __launch_bounds__(256) void recompute_select_kernel(
    const float* __restrict__ x,
    const float* __restrict__ We,
    const float* __restrict__ be,
    const float* __restrict__ pre,
    const int*   __restrict__ cand_idx,
    const int*   __restrict__ cand_cnt,
    int cap,
    float* __restrict__ features,
    float* __restrict__ valsT,           // [KTOP][NROWS]
    int*   __restrict__ idxT)            // [KTOP][NROWS]
{
    __shared__ float xr[D_MODEL];
    __shared__ float cv[CAPMAX];
    __shared__ int   ci[CAPMAX];
    __shared__ float av_s[CAPMAX];
    __shared__ unsigned cnt_part[4];
    __shared__ unsigned hist[2048];
    __shared__ unsigned part[2][256];
    __shared__ int s_thr;
    __shared__ unsigned s_cnt;

    const int n    = blockIdx.x;
    const int t    = threadIdx.x;
    const int lane = t & 63;
    const int w    = t >> 6;
    const int rawcnt = cand_cnt[n];
    int cnt = rawcnt < cap ? rawcnt : cap;

    float4* frow = reinterpret_cast<float4*>(features + (size_t)n * DICT);
    const float4 z4 = make_float4(0.f, 0.f, 0.f, 0.f);
    #pragma unroll 8
    for (int i = t; i < DICT / 4; i += 256) frow[i] = z4;

    for (int i = t; i < D_MODEL / 4; i += 256)
        reinterpret_cast<float4*>(xr)[i] =
            reinterpret_cast<const float4*>(x + (size_t)n * D_MODEL)[i];
    for (int c = t; c < cnt; c += 256) ci[c] = cand_idx[(size_t)n * cap + c];
    __syncthreads();

    float av = -INFINITY;
    if (t < cnt) av = pre[(size_t)n * DICT + ci[t]];
    if (t < CAPMAX) av_s[t] = av;
    __syncthreads();

    float lo = 0.f, hi = 16.f;
    for (int it = 0; it < 18; ++it) {
        const float mid = 0.5f * (lo + hi);
        unsigned long long b = __ballot(av >= mid);
        if (lane == 0) cnt_part[w] = (unsigned)__popcll(b);
        __syncthreads();
        const int c32 = (int)(cnt_part[0] + cnt_part[1] + cnt_part[2] + cnt_part[3]);
        if (c32 >= KTOP) lo = mid; else hi = mid;
        __syncthreads();
    }
    float cutoff  = lo - 0.08f;
    float sure_hi = lo + 0.17f;

    const bool ok = (rawcnt <= cap) && (cnt >= KTOP) && (cutoff >= T_OPT);
    if (!ok) {
        for (int i = t; i < 2048; i += 256) hist[i] = 0;
        if (t == 0) { s_thr = -1; s_cnt = 0; }
        __syncthreads();
        const float4* srcp = reinterpret_cast<const float4*>(pre + (size_t)n * DICT);
        for (int p = 0; p < DICT / 1024; ++p) {
            float4 v = srcp[t + 256 * p];
            float e[4] = {v.x, v.y, v.z, v.w};
            #pragma unroll
            for (int j = 0; j < 4; ++j)
                if (e[j] > 0.f)
                    atomicAdd(&hist[__builtin_bit_cast(unsigned, e[j]) >> 20], 1u);
        }
        __syncthreads();
        unsigned hv[8];
        unsigned local = 0;
        #pragma unroll
        for (int b = 0; b < 8; ++b) { hv[b] = hist[t * 8 + b]; local += hv[b]; }
        part[0][t] = local;
        __syncthreads();
        int sb = 0;
        for (int s = 1; s < 256; s <<= 1) {
            unsigned v2 = part[sb][t];
            if (t + s < 256) v2 += part[sb][t + s];
            part[sb ^ 1][t] = v2;
            sb ^= 1;
            __syncthreads();
        }
        const unsigned above = (t < 255) ? part[sb][t + 1] : 0;
        unsigned cum = above;
        int mybin = -1;
        #pragma unroll
        for (int b = 7; b >= 0; --b) {
            cum += hv[b];
            if (mybin < 0 && cum >= NCAND_FB) mybin = t * 8 + b;
        }
        if (mybin >= 0) atomicMax(&s_thr, mybin);
        __syncthreads();
        const unsigned thrb = (s_thr < 0) ? 0u : (unsigned)s_thr;
        for (int p = 0; p < DICT / 1024; ++p) {
            float4 v = srcp[t + 256 * p];
            float e[4] = {v.x, v.y, v.z, v.w};
            #pragma unroll
            for (int j = 0; j < 4; ++j) {
                if (e[j] > 0.f &&
                    (__builtin_bit_cast(unsigned, e[j]) >> 20) >= thrb) {
                    unsigned pos = atomicAdd(&s_cnt, 1u);
                    if (pos < (unsigned)cap) {
                        ci[pos]   = (t + 256 * p) * 4 + j;
                        av_s[pos] = e[j];
                    }
                }
            }
        }
        __syncthreads();
        cnt = (int)min(s_cnt, (unsigned)cap);
        av = (t < cnt) ? av_s[t] : -INFINITY;
        lo = 0.f; hi = 16.f;
        for (int it = 0; it < 18; ++it) {
            const float mid = 0.5f * (lo + hi);
            unsigned long long b = __ballot(av >= mid);
            if (lane == 0) cnt_part[w] = (unsigned)__popcll(b);
            __syncthreads();
            const int c32 = (int)(cnt_part[0] + cnt_part[1] + cnt_part[2] + cnt_part[3]);
            if (c32 >= KTOP) lo = mid; else hi = mid;
            __syncthreads();
        }
        cutoff  = lo - 0.08f;
        sure_hi = lo + 0.17f;
    }

    for (int c = w; c < cnt; c += 4) {
        const float a_v = av_s[c];
        if (a_v < cutoff)   { if (lane == 0) cv[c] = -INFINITY; continue; }
        if (a_v > sure_hi)  { if (lane == 0) cv[c] = a_v;       continue; }
        const int idx = ci[c];
        const float4* wrow = reinterpret_cast<const float4*>(We + (size_t)idx * D_MODEL);
        const float4* xro  = reinterpret_cast<const float4*>(xr);
        float s = 0.f;
        #pragma unroll
        for (int p = 0; p < 8; ++p) {
            float4 a = xro[lane + 64 * p];
            float4 b = wrow[lane + 64 * p];
            s = fmaf(a.x, b.x, s); s = fmaf(a.y, b.y, s);
            s = fmaf(a.z, b.z, s); s = fmaf(a.w, b.w, s);
        }
        #pragma unroll
        for (int sh = 1; sh < 64; sh <<= 1) s += __shfl_xor(s, sh);
        if (lane == 0) cv[c] = s + be[idx];
    }
    __syncthreads();

    if (w == 0) {
        float pv[CAPMAX / 64];
        int   pi[CAPMAX / 64];
        #pragma unroll
        for (int qq = 0; qq < CAPMAX / 64; ++qq) {
            const int c = lane + 64 * qq;
            const bool okc = c < cnt;
            pv[qq] = okc ? cv[c] : -INFINITY;
            pi[qq] = okc ? ci[c] : 0x7fffffff;
        }
        for (int r = 0; r < KTOP; ++r) {
            float bv = pv[0]; int bi = pi[0]; int bq = 0;
            #pragma unroll
            for (int qq = 1; qq < CAPMAX / 64; ++qq)
                if (pv[qq] > bv || (pv[qq] == bv && pi[qq] < bi)) {
                    bv = pv[qq]; bi = pi[qq]; bq = qq;
                }
            float gv = bv; int gi = bi;
            #pragma unroll
            for (int s = 1; s < 64; s <<= 1) {
                float ov = __shfl_xor(gv, s);
                int   oi = __shfl_xor(gi, s);
                if (ov > gv || (ov == gv && oi < gi)) { gv = ov; gi = oi; }
            }
            if (bi == gi) pv[bq] = -INFINITY;
            if (lane == 0) {
                const bool valid = (gi != 0x7fffffff) && (gv != -INFINITY);
                const float rv = (valid && gv > 0.f) ? gv : 0.f;
                valsT[r * NROWS + n] = rv;
                idxT[r * NROWS + n]  = valid ? gi : 0;
                if (valid) features[(size_t)n * DICT + gi] = rv;
            }
        }
    }
}

// ---------------------------------------------------------------------------
// Decoder: block per d, full Wd row (128KB) in LDS, 1024 threads.
// ---------------------------------------------------------------------------
__global__ __launch_bounds__(1024) void decoder_kernel(
    const float* __restrict__ Wd,
    const float* __restrict__ bd,
    const float* __restrict__ valsT,     // [KTOP][NROWS]
    const int*   __restrict__ idxT,      // [KTOP][NROWS]
    float* __restrict__ recon)
{
    __shared__ float wrow[DICT];         // 128 KB
    const int d = blockIdx.x;
    const int t = threadIdx.x;
    const float* src = Wd + (size_t)d * DICT;

    for (int i = t; i < DICT / 4; i += 1024)
        reinterpret_cast<float4*>(wrow)[i] =
            reinterpret_cast<const float4*>(src)[i];
    __syncthreads();

    const float b = bd[d];
    #pragma unroll
    for (int u = 0; u < NROWS / 1024; ++u) {
        const int n = t + 1024 * u;
        float a0 = 0.f, a1 = 0.f, a2 = 0.f, a3 = 0.f;
        #pragma unroll
        for (int k = 0; k < KTOP; k += 8) {
            float v0 = valsT[(k + 0) * NROWS + n];
            float v1 = valsT[(k + 1) * NROWS + n];
            float v2 = valsT[(k + 2) * NROWS + n];
            float v3 = valsT[(k + 3) * NROWS + n];
            float v4 = valsT[(k + 4) * NROWS + n];
            float v5 = valsT[(k + 5) * NROWS + n];
            float v6 = valsT[(k + 6) * NROWS + n];
            float v7 = valsT[(k + 7) * NROWS + n];
            int i0 = idxT[(k + 0) * NROWS + n];
            int i1 = idxT[(k + 1) * NROWS + n];
            int i2 = idxT[(k + 2) * NROWS + n];
            int i3 = idxT[(k + 3) * NROWS + n];
            int i4 = idxT[(k + 4) * NROWS + n];
            int i5 = idxT[(k + 5) * NROWS + n];
            int i6 = idxT[(k + 6) * NROWS + n];
            int i7 = idxT[(k + 7) * NROWS + n];
            a0 = fmaf(v0, wrow[i0], a0);
            a1 = fmaf(v1, wrow[i1], a1);
            a2 = fmaf(v2, wrow[i2], a2);
            a3 = fmaf(v3, wrow[i3], a3);
            a0 = fmaf(v4, wrow[i4], a0);
            a1 = fmaf(v5, wrow[i5], a1);
            a2 = fmaf(v6, wrow[i6], a2);
            a3 = fmaf(v7, wrow[i7], a3);
        }
        recon[(size_t)n * D_MODEL + d] = ((a0 + a1) + (a2 + a3)) + b;
    }
}

// ---------------------------------------------------------------------------
extern "C" void kernel_launch(void* const* d_in, const int* in_sizes, int n_in,
                              void* d_out, int out_size, void* d_ws, size_t ws_size,
                              hipStream_t stream)
{
    const float* x  = (const float*)d_in[0];
    const float* We = (const float*)d_in[1];
    const float* be = (const float*)d_in[2];
    const float* Wd = (const float*)d_in[3];
    const float* bd = (const float*)d_in[4];

    float* out      = (float*)d_out;
    float* recon    = out;
    float* features = out + (size_t)NROWS * D_MODEL;
    float* pre      = features + (size_t)NROWS * DICT;

    // bf16 tiled operands parked in the features region (overwritten by
    // recompute's per-row zeroing of features)
    unsigned short* webf = (unsigned short*)features;                 // 128 MB
    unsigned short* xbf  = webf + (size_t)TNB * NT_K * 8192;          // + 8 MB

    long cap_l = (long)(ws_size / 4 - (size_t)NROWS * (1 + 2 * KTOP)) / NROWS;
    int cap = (int)(cap_l < 64 ? 64 : (cap_l > CAPMAX ? CAPMAX : cap_l));

    char* ws = (char*)d_ws;
    int*   ws_cand  = (int*)ws;
    int*   ws_cnt   = (int*)(ws + (size_t)NROWS * cap * 4);
    float* ws_valsT = (float*)(ws + (size_t)NROWS * (cap + 1) * 4);
    int*   ws_idxT  = (int*)(ws + (size_t)NROWS * (cap + 1 + KTOP) * 4);

    // 0) zero per-row candidate counters
    hipMemsetAsync(ws_cnt, 0, (size_t)NROWS * sizeof(int), stream);

    // 1) convert + tile + swizzle operands to bf16 (BK=32 layout)
    const int conv_blocks = (int)(((size_t)NROWS * 64 + (size_t)DICT * 64) / 256);
    convert_tiles<<<conv_blocks, 256, 0, stream>>>(x, We, xbf, webf);

    // 2) encoder GEMM (2 blocks/CU) -> approx pre_acts + candidate collection
    encoder_bf16<<<TMB * TNB, 512, 0, stream>>>(
        xbf, webf, be, pre, ws_cand, ws_cnt, cap);

    // 3) banded exact recompute + features zeroing + top-32 + scatter
    recompute_select_kernel<<<NROWS, 256, 0, stream>>>(
        x, We, be, pre, ws_cand, ws_cnt, cap, features, ws_valsT, ws_idxT);

    // 4) sparse decoder
    decoder_kernel<<<D_MODEL, 1024, 0, stream>>>(
        Wd, bd, ws_valsT, ws_idxT, recon);
}

// Round 18
// 784.653 us; speedup vs baseline: 1.0326x; 1.0326x over previous
//
#include <hip/hip_runtime.h>
#include <cstddef>
#include <cstdint>
#include <cmath>

#define D_MODEL 2048
#define DICT    32768
#define KTOP    32
#define NCAND_FB 96         // fallback hist margin (rank cum >= 96)
#define CAPMAX  256
#define T_OPT   2.70f       // epilogue collect threshold
#define BKT     32                  // K-tile depth (64KB LDS -> 2 blocks/CU)
#define NT_K    (D_MODEL / BKT)     // 64 K-tiles
#define NROWS   2048
#define TMB     (NROWS / 256)       // 8  row tiles
#define TNB     (DICT / 256)        // 128 col tiles

// r18 swizzle for 64-byte rows: key = ((row>>1)&7)<<4. Bank-quad becomes
// (r1, r2, r0^r3): each of 8 quads hit exactly twice per 16 lanes -> 2-way
// (free, m136). r17's carried-over (row&7)<<4 key CANCELLED the natural
// row-parity bank bit at this stride -> 16-way conflict (2.5e7 measured).
#define SWZ64(byteoff, row) ((byteoff) ^ ((((row) >> 1) & 7) << 4))

typedef float    f32x4  __attribute__((ext_vector_type(4)));
typedef __bf16   bf16x8 __attribute__((ext_vector_type(8)));
typedef unsigned short us8 __attribute__((ext_vector_type(8)));

__device__ __forceinline__ unsigned short f2bf_rne(float f) {
    unsigned u = __builtin_bit_cast(unsigned, f);
    unsigned r = u + 0x7fffu + ((u >> 16) & 1u);
    return (unsigned short)(r >> 16);
}

__device__ __forceinline__ void gload16(const void* g, const void* s) {
    __builtin_amdgcn_global_load_lds(
        (const __attribute__((address_space(1))) unsigned int*)g,
        (__attribute__((address_space(3))) unsigned int*)s, 16, 0, 0);
}

// ---------------------------------------------------------------------------
// Convert x and We f32 -> bf16, pre-tiled per 256-row tile into 64 K-tiles of
// 32 k. Per (tile,ktile): [half(row>=128) 8KB][rloc 0..127][64B row], with
// SWZ64 baked in (GEMM ds_read uses the identical formula).
// ---------------------------------------------------------------------------
__global__ __launch_bounds__(256) void convert_tiles(
    const float* __restrict__ x,
    const float* __restrict__ We,
    unsigned short* __restrict__ xbf,     // [TMB][NT_K][8192] ushorts
    unsigned short* __restrict__ webf)    // [TNB][NT_K][8192] ushorts
{
    const size_t NX = (size_t)NROWS * 64;
    size_t id = (size_t)blockIdx.x * 256 + threadIdx.x;

    const float* src;
    unsigned short* dstb;
    int row, s;
    if (id < NX) {
        row = (int)(id >> 6); s = (int)(id & 63);
        src = x + (size_t)row * D_MODEL + s * 32;
        dstb = xbf + ((size_t)(row >> 8) * NT_K + s) * 8192
                   + ((row >> 7) & 1) * 4096;
    } else {
        id -= NX;
        row = (int)(id >> 6); s = (int)(id & 63);
        src = We + (size_t)row * D_MODEL + s * 32;
        dstb = webf + ((size_t)(row >> 8) * NT_K + s) * 8192
                    + ((row >> 7) & 1) * 4096;
    }
    const int rloc = row & 127;

    #pragma unroll
    for (int qc = 0; qc < 4; ++qc) {
        float4 v0 = reinterpret_cast<const float4*>(src)[qc * 2];
        float4 v1 = reinterpret_cast<const float4*>(src)[qc * 2 + 1];
        us8 c;
        c[0] = f2bf_rne(v0.x); c[1] = f2bf_rne(v0.y);
        c[2] = f2bf_rne(v0.z); c[3] = f2bf_rne(v0.w);
        c[4] = f2bf_rne(v1.x); c[5] = f2bf_rne(v1.y);
        c[6] = f2bf_rne(v1.z); c[7] = f2bf_rne(v1.w);
        const int byteoff = SWZ64(rloc * 64 + qc * 16, rloc);
        *reinterpret_cast<us8*>(reinterpret_cast<char*>(dstb) + byteoff) = c;
    }
}

// ---------------------------------------------------------------------------
// Encoder GEMM: 256x256 tile, BK=32, LDS 64KB -> 2 blocks/CU (m114 CU-level
// overlap: one block drains ds_reads while the other issues MFMA). 2 phases
// per K-tile: P1{12 reads; bar; lgkm0; 16 MFMA; bar} P2{stage 4 half-tiles
// (u+2); vmcnt(4); bar; 16 MFMA; bar}. vmcnt(4) retires tile u+1 exactly;
// stages overwrite [cur] whose reads drained at P1's lgkmcnt(0).
// ---------------------------------------------------------------------------
__global__ __launch_bounds__(512, 2) void encoder_bf16(
    const unsigned short* __restrict__ xbf,
    const unsigned short* __restrict__ webf,
    const float* __restrict__ bias,
    float* __restrict__ C,
    int* __restrict__ cand_idx,           // [NROWS][cap]
    int* __restrict__ cand_cnt,           // [NROWS], pre-zeroed
    int cap)
{
    __shared__ __align__(16) unsigned short Ab[2][2][4096];   // [dbuf][half] 8KB
    __shared__ __align__(16) unsigned short Bb[2][2][4096];

    const int t    = threadIdx.x;
    const int lane = t & 63;
    const int w    = t >> 6;        // 0..7
    const int wm   = w >> 2;        // 0..1  (128-row half = A half)
    const int wn   = w & 3;         // 0..3  (64-col slice)
    const int hB   = wn >> 1;       // B half index

    const int bid = blockIdx.x;
    const int swz = (bid & 7) * (TMB * TNB / 8) + (bid >> 3);
    const int mt  = swz & (TMB - 1);
    const int nt  = swz >> 3;

    const char* As = (const char*)xbf  + (size_t)mt * (NT_K * 16384);
    const char* Bs = (const char*)webf + (size_t)nt * (NT_K * 16384);

    f32x4 acc[8][4];
    #pragma unroll
    for (int i = 0; i < 8; ++i)
        #pragma unroll
        for (int j = 0; j < 4; ++j) acc[i][j] = (f32x4)0.f;

    const int soff = t * 16;        // byte offset in 8KB half-tile
    const int dsti = t * 8;         // ushort idx in LDS half-buf

    #define STAGE_A(buf, u, h) \
        gload16(As + (size_t)(u) * 16384 + (h) * 8192 + soff, &Ab[buf][h][dsti])
    #define STAGE_B(buf, u, h) \
        gload16(Bs + (size_t)(u) * 16384 + (h) * 8192 + soff, &Bb[buf][h][dsti])

    bf16x8 a[8], b[4];
    const int q16 = (lane >> 4) * 16;

    #define LDA_ALL() do {                                                   \
        _Pragma("unroll") for (int i = 0; i < 8; ++i) {                      \
            const int rl = i * 16 + (lane & 15);                             \
            const int by = SWZ64(rl * 64 + q16, rl);                         \
            a[i] = __builtin_bit_cast(bf16x8,                                \
                *reinterpret_cast<const us8*>(                               \
                    (const char*)&Ab[cur][wm][0] + by));                     \
        } } while (0)
    #define LDB_ALL() do {                                                   \
        _Pragma("unroll") for (int j = 0; j < 4; ++j) {                      \
            const int cl = (wn & 1) * 64 + j * 16 + (lane & 15);             \
            const int by = SWZ64(cl * 64 + q16, cl);                         \
            b[j] = __builtin_bit_cast(bf16x8,                                \
                *reinterpret_cast<const us8*>(                               \
                    (const char*)&Bb[cur][hB][0] + by));                     \
        } } while (0)
    #define MMA_HALF(ib) do {                                                \
        _Pragma("unroll") for (int i = 0; i < 4; ++i)                        \
        _Pragma("unroll") for (int j = 0; j < 4; ++j)                        \
            acc[(ib) + i][j] = __builtin_amdgcn_mfma_f32_16x16x32_bf16(      \
                a[(ib) + i], b[j], acc[(ib) + i][j], 0, 0, 0);               \
    } while (0)

    // prologue: stage tiles 0 and 1 (8 loads/thread); retire tile 0
    STAGE_B(0, 0, 0); STAGE_B(0, 0, 1);
    STAGE_A(0, 0, 0); STAGE_A(0, 0, 1);
    STAGE_B(1, 1, 0); STAGE_B(1, 1, 1);
    STAGE_A(1, 1, 0); STAGE_A(1, 1, 1);
    asm volatile("s_waitcnt vmcnt(4)" ::: "memory");
    __builtin_amdgcn_sched_barrier(0);
    __builtin_amdgcn_s_barrier();

    int cur = 0;
    for (int u = 0; u < NT_K; ++u) {
        // ---- P1: all 12 frag reads; MFMA rows 0-3
        LDA_ALL();
        LDB_ALL();
        __builtin_amdgcn_s_barrier();
        asm volatile("s_waitcnt lgkmcnt(0)" ::: "memory");
        __builtin_amdgcn_sched_barrier(0);
        __builtin_amdgcn_s_setprio(1);
        MMA_HALF(0);
        __builtin_amdgcn_s_setprio(0);
        __builtin_amdgcn_s_barrier();

        // ---- P2: stage tile u+2 into [cur]; counted vmcnt; MFMA rows 4-7
        if (u + 2 < NT_K) {
            STAGE_B(cur, u + 2, 0); STAGE_B(cur, u + 2, 1);
            STAGE_A(cur, u + 2, 0); STAGE_A(cur, u + 2, 1);
            asm volatile("s_waitcnt vmcnt(4)" ::: "memory");
        } else {
            asm volatile("s_waitcnt vmcnt(0)" ::: "memory");
        }
        __builtin_amdgcn_sched_barrier(0);
        __builtin_amdgcn_s_barrier();
        __builtin_amdgcn_s_setprio(1);
        MMA_HALF(4);
        __builtin_amdgcn_s_setprio(0);
        __builtin_amdgcn_s_barrier();

        cur ^= 1;
    }
    #undef STAGE_A
    #undef STAGE_B
    #undef LDA_ALL
    #undef LDB_ALL
    #undef MMA_HALF

    const int m0 = mt * 256, n0 = nt * 256;
    float bvj[4];
    #pragma unroll
    for (int j = 0; j < 4; ++j)
        bvj[j] = bias[n0 + wn * 64 + j * 16 + (lane & 15)];

    // pure store loop (no branches/atomics)
    #pragma unroll
    for (int j = 0; j < 4; ++j) {
        const int col = n0 + wn * 64 + j * 16 + (lane & 15);
        #pragma unroll
        for (int i = 0; i < 8; ++i) {
            const int rowb = m0 + wm * 128 + i * 16 + ((lane >> 4) * 4);
            #pragma unroll
            for (int r = 0; r < 4; ++r)
                C[(size_t)(rowb + r) * DICT + col] = acc[i][j][r] + bvj[j];
        }
    }

    // collection: thread-local 4-slot compare pass, then short emission.
    int nh = 0, h0 = 0, h1 = 0, h2 = 0, h3 = 0;
    #pragma unroll
    for (int j = 0; j < 4; ++j) {
        const int col = n0 + wn * 64 + j * 16 + (lane & 15);
        #pragma unroll
        for (int i = 0; i < 8; ++i) {
            const int rowb = m0 + wm * 128 + i * 16 + ((lane >> 4) * 4);
            #pragma unroll
            for (int r = 0; r < 4; ++r) {
                if (acc[i][j][r] + bvj[j] >= T_OPT) {
                    const int enc = ((rowb + r) << 15) | col;
                    if      (nh == 0) h0 = enc;
                    else if (nh == 1) h1 = enc;
                    else if (nh == 2) h2 = enc;
                    else if (nh == 3) h3 = enc;
                    else {
                        const int row2 = enc >> 15;
                        const int pos2 = atomicAdd(&cand_cnt[row2], 1);
                        if (pos2 < cap)
                            cand_idx[(size_t)row2 * cap + pos2] = enc & 0x7FFF;
                    }
                    ++nh;
                }
            }
        }
    }
    #pragma unroll
    for (int s2 = 0; s2 < 4; ++s2) {
        if (nh > s2) {
            const int enc = (s2 == 0) ? h0 : (s2 == 1) ? h1
                          : (s2 == 2) ? h2 : h3;
            const int row2 = enc >> 15;
            const int pos  = atomicAdd(&cand_cnt[row2], 1);
            if (pos < cap)
                cand_idx[(size_t)row2 * cap + pos] = enc & 0x7FFF;
        }
    }
}

// ---------------------------------------------------------------------------
// Exact f32 recompute + features-row zeroing + exact top-32 + scatter.
// Three approx bands: skip / sure-in (use approx) / ambiguous (exact dot).
// Fallback hist path for degenerate rows (correctness never depends on T_OPT).
// ---------------------------------------------------------------------------
__global__ __launch_bounds__(256) void recompute_select_kernel(
    const float* __restrict__ x,
    const float* __restrict__ We,
    const float* __restrict__ be,
    const float* __restrict__ pre,
    const int*   __restrict__ cand_idx,
    const int*   __restrict__ cand_cnt,
    int cap,
    float* __restrict__ features,
    float* __restrict__ valsT,           // [KTOP][NROWS]
    int*   __restrict__ idxT)            // [KTOP][NROWS]
{
    __shared__ float xr[D_MODEL];
    __shared__ float cv[CAPMAX];
    __shared__ int   ci[CAPMAX];
    __shared__ float av_s[CAPMAX];
    __shared__ unsigned cnt_part[4];
    __shared__ unsigned hist[2048];
    __shared__ unsigned part[2][256];
    __shared__ int s_thr;
    __shared__ unsigned s_cnt;

    const int n    = blockIdx.x;
    const int t    = threadIdx.x;
    const int lane = t & 63;
    const int w    = t >> 6;
    const int rawcnt = cand_cnt[n];
    int cnt = rawcnt < cap ? rawcnt : cap;

    float4* frow = reinterpret_cast<float4*>(features + (size_t)n * DICT);
    const float4 z4 = make_float4(0.f, 0.f, 0.f, 0.f);
    #pragma unroll 8
    for (int i = t; i < DICT / 4; i += 256) frow[i] = z4;

    for (int i = t; i < D_MODEL / 4; i += 256)
        reinterpret_cast<float4*>(xr)[i] =
            reinterpret_cast<const float4*>(x + (size_t)n * D_MODEL)[i];
    for (int c = t; c < cnt; c += 256) ci[c] = cand_idx[(size_t)n * cap + c];
    __syncthreads();

    float av = -INFINITY;
    if (t < cnt) av = pre[(size_t)n * DICT + ci[t]];
    if (t < CAPMAX) av_s[t] = av;
    __syncthreads();

    float lo = 0.f, hi = 16.f;
    for (int it = 0; it < 18; ++it) {
        const float mid = 0.5f * (lo + hi);
        unsigned long long b = __ballot(av >= mid);
        if (lane == 0) cnt_part[w] = (unsigned)__popcll(b);
        __syncthreads();
        const int c32 = (int)(cnt_part[0] + cnt_part[1] + cnt_part[2] + cnt_part[3]);
        if (c32 >= KTOP) lo = mid; else hi = mid;
        __syncthreads();
    }
    float cutoff  = lo - 0.08f;
    float sure_hi = lo + 0.17f;

    const bool ok = (rawcnt <= cap) && (cnt >= KTOP) && (cutoff >= T_OPT);
    if (!ok) {
        for (int i = t; i < 2048; i += 256) hist[i] = 0;
        if (t == 0) { s_thr = -1; s_cnt = 0; }
        __syncthreads();
        const float4* srcp = reinterpret_cast<const float4*>(pre + (size_t)n * DICT);
        for (int p = 0; p < DICT / 1024; ++p) {
            float4 v = srcp[t + 256 * p];
            float e[4] = {v.x, v.y, v.z, v.w};
            #pragma unroll
            for (int j = 0; j < 4; ++j)
                if (e[j] > 0.f)
                    atomicAdd(&hist[__builtin_bit_cast(unsigned, e[j]) >> 20], 1u);
        }
        __syncthreads();
        unsigned hv[8];
        unsigned local = 0;
        #pragma unroll
        for (int b = 0; b < 8; ++b) { hv[b] = hist[t * 8 + b]; local += hv[b]; }
        part[0][t] = local;
        __syncthreads();
        int sb = 0;
        for (int s = 1; s < 256; s <<= 1) {
            unsigned v2 = part[sb][t];
            if (t + s < 256) v2 += part[sb][t + s];
            part[sb ^ 1][t] = v2;
            sb ^= 1;
            __syncthreads();
        }
        const unsigned above = (t < 255) ? part[sb][t + 1] : 0;
        unsigned cum = above;
        int mybin = -1;
        #pragma unroll
        for (int b = 7; b >= 0; --b) {
            cum += hv[b];
            if (mybin < 0 && cum >= NCAND_FB) mybin = t * 8 + b;
        }
        if (mybin >= 0) atomicMax(&s_thr, mybin);
        __syncthreads();
        const unsigned thrb = (s_thr < 0) ? 0u : (unsigned)s_thr;
        for (int p = 0; p < DICT / 1024; ++p) {
            float4 v = srcp[t + 256 * p];
            float e[4] = {v.x, v.y, v.z, v.w};
            #pragma unroll
            for (int j = 0; j < 4; ++j) {
                if (e[j] > 0.f &&
                    (__builtin_bit_cast(unsigned, e[j]) >> 20) >= thrb) {
                    unsigned pos = atomicAdd(&s_cnt, 1u);
                    if (pos < (unsigned)cap) {
                        ci[pos]   = (t + 256 * p) * 4 + j;
                        av_s[pos] = e[j];
                    }
                }
            }
        }
        __syncthreads();
        cnt = (int)min(s_cnt, (unsigned)cap);
        av = (t < cnt) ? av_s[t] : -INFINITY;
        lo = 0.f; hi = 16.f;
        for (int it = 0; it < 18; ++it) {
            const float mid = 0.5f * (lo + hi);
            unsigned long long b = __ballot(av >= mid);
            if (lane == 0) cnt_part[w] = (unsigned)__popcll(b);
            __syncthreads();
            const int c32 = (int)(cnt_part[0] + cnt_part[1] + cnt_part[2] + cnt_part[3]);
            if (c32 >= KTOP) lo = mid; else hi = mid;
            __syncthreads();
        }
        cutoff  = lo - 0.08f;
        sure_hi = lo + 0.17f;
    }

    for (int c = w; c < cnt; c += 4) {
        const float a_v = av_s[c];
        if (a_v < cutoff)   { if (lane == 0) cv[c] = -INFINITY; continue; }
        if (a_v > sure_hi)  { if (lane == 0) cv[c] = a_v;       continue; }
        const int idx = ci[c];
        const float4* wrow = reinterpret_cast<const float4*>(We + (size_t)idx * D_MODEL);
        const float4* xro  = reinterpret_cast<const float4*>(xr);
        float s = 0.f;
        #pragma unroll
        for (int p = 0; p < 8; ++p) {
            float4 a = xro[lane + 64 * p];
            float4 b = wrow[lane + 64 * p];
            s = fmaf(a.x, b.x, s); s = fmaf(a.y, b.y, s);
            s = fmaf(a.z, b.z, s); s = fmaf(a.w, b.w, s);
        }
        #pragma unroll
        for (int sh = 1; sh < 64; sh <<= 1) s += __shfl_xor(s, sh);
        if (lane == 0) cv[c] = s + be[idx];
    }
    __syncthreads();

    if (w == 0) {
        float pv[CAPMAX / 64];
        int   pi[CAPMAX / 64];
        #pragma unroll
        for (int qq = 0; qq < CAPMAX / 64; ++qq) {
            const int c = lane + 64 * qq;
            const bool okc = c < cnt;
            pv[qq] = okc ? cv[c] : -INFINITY;
            pi[qq] = okc ? ci[c] : 0x7fffffff;
        }
        for (int r = 0; r < KTOP; ++r) {
            float bv = pv[0]; int bi = pi[0]; int bq = 0;
            #pragma unroll
            for (int qq = 1; qq < CAPMAX / 64; ++qq)
                if (pv[qq] > bv || (pv[qq] == bv && pi[qq] < bi)) {
                    bv = pv[qq]; bi = pi[qq]; bq = qq;
                }
            float gv = bv; int gi = bi;
            #pragma unroll
            for (int s = 1; s < 64; s <<= 1) {
                float ov = __shfl_xor(gv, s);
                int   oi = __shfl_xor(gi, s);
                if (ov > gv || (ov == gv && oi < gi)) { gv = ov; gi = oi; }
            }
            if (bi == gi) pv[bq] = -INFINITY;
            if (lane == 0) {
                const bool valid = (gi != 0x7fffffff) && (gv != -INFINITY);
                const float rv = (valid && gv > 0.f) ? gv : 0.f;
                valsT[r * NROWS + n] = rv;
                idxT[r * NROWS + n]  = valid ? gi : 0;
                if (valid) features[(size_t)n * DICT + gi] = rv;
            }
        }
    }
}

// ---------------------------------------------------------------------------
// Decoder: block per d, full Wd row (128KB) in LDS, 1024 threads.
// ---------------------------------------------------------------------------
__global__ __launch_bounds__(1024) void decoder_kernel(
    const float* __restrict__ Wd,
    const float* __restrict__ bd,
    const float* __restrict__ valsT,     // [KTOP][NROWS]
    const int*   __restrict__ idxT,      // [KTOP][NROWS]
    float* __restrict__ recon)
{
    __shared__ float wrow[DICT];         // 128 KB
    const int d = blockIdx.x;
    const int t = threadIdx.x;
    const float* src = Wd + (size_t)d * DICT;

    for (int i = t; i < DICT / 4; i += 1024)
        reinterpret_cast<float4*>(wrow)[i] =
            reinterpret_cast<const float4*>(src)[i];
    __syncthreads();

    const float b = bd[d];
    #pragma unroll
    for (int u = 0; u < NROWS / 1024; ++u) {
        const int n = t + 1024 * u;
        float a0 = 0.f, a1 = 0.f, a2 = 0.f, a3 = 0.f;
        #pragma unroll
        for (int k = 0; k < KTOP; k += 8) {
            float v0 = valsT[(k + 0) * NROWS + n];
            float v1 = valsT[(k + 1) * NROWS + n];
            float v2 = valsT[(k + 2) * NROWS + n];
            float v3 = valsT[(k + 3) * NROWS + n];
            float v4 = valsT[(k + 4) * NROWS + n];
            float v5 = valsT[(k + 5) * NROWS + n];
            float v6 = valsT[(k + 6) * NROWS + n];
            float v7 = valsT[(k + 7) * NROWS + n];
            int i0 = idxT[(k + 0) * NROWS + n];
            int i1 = idxT[(k + 1) * NROWS + n];
            int i2 = idxT[(k + 2) * NROWS + n];
            int i3 = idxT[(k + 3) * NROWS + n];
            int i4 = idxT[(k + 4) * NROWS + n];
            int i5 = idxT[(k + 5) * NROWS + n];
            int i6 = idxT[(k + 6) * NROWS + n];
            int i7 = idxT[(k + 7) * NROWS + n];
            a0 = fmaf(v0, wrow[i0], a0);
            a1 = fmaf(v1, wrow[i1], a1);
            a2 = fmaf(v2, wrow[i2], a2);
            a3 = fmaf(v3, wrow[i3], a3);
            a0 = fmaf(v4, wrow[i4], a0);
            a1 = fmaf(v5, wrow[i5], a1);
            a2 = fmaf(v6, wrow[i6], a2);
            a3 = fmaf(v7, wrow[i7], a3);
        }
        recon[(size_t)n * D_MODEL + d] = ((a0 + a1) + (a2 + a3)) + b;
    }
}

// ---------------------------------------------------------------------------
extern "C" void kernel_launch(void* const* d_in, const int* in_sizes, int n_in,
                              void* d_out, int out_size, void* d_ws, size_t ws_size,
                              hipStream_t stream)
{
    const float* x  = (const float*)d_in[0];
    const float* We = (const float*)d_in[1];
    const float* be = (const float*)d_in[2];
    const float* Wd = (const float*)d_in[3];
    const float* bd = (const float*)d_in[4];

    float* out      = (float*)d_out;
    float* recon    = out;
    float* features = out + (size_t)NROWS * D_MODEL;
    float* pre      = features + (size_t)NROWS * DICT;

    // bf16 tiled operands parked in the features region (overwritten by
    // recompute's per-row zeroing of features)
    unsigned short* webf = (unsigned short*)features;                 // 128 MB
    unsigned short* xbf  = webf + (size_t)TNB * NT_K * 8192;          // + 8 MB

    long cap_l = (long)(ws_size / 4 - (size_t)NROWS * (1 + 2 * KTOP)) / NROWS;
    int cap = (int)(cap_l < 64 ? 64 : (cap_l > CAPMAX ? CAPMAX : cap_l));

    char* ws = (char*)d_ws;
    int*   ws_cand  = (int*)ws;
    int*   ws_cnt   = (int*)(ws + (size_t)NROWS * cap * 4);
    float* ws_valsT = (float*)(ws + (size_t)NROWS * (cap + 1) * 4);
    int*   ws_idxT  = (int*)(ws + (size_t)NROWS * (cap + 1 + KTOP) * 4);

    // 0) zero per-row candidate counters
    hipMemsetAsync(ws_cnt, 0, (size_t)NROWS * sizeof(int), stream);

    // 1) convert + tile + swizzle operands to bf16 (BK=32 layout, SWZ64)
    const int conv_blocks = (int)(((size_t)NROWS * 64 + (size_t)DICT * 64) / 256);
    convert_tiles<<<conv_blocks, 256, 0, stream>>>(x, We, xbf, webf);

    // 2) encoder GEMM (2 blocks/CU) -> approx pre_acts + candidate collection
    encoder_bf16<<<TMB * TNB, 512, 0, stream>>>(
        xbf, webf, be, pre, ws_cand, ws_cnt, cap);

    // 3) banded exact recompute + features zeroing + top-32 + scatter
    recompute_select_kernel<<<NROWS, 256, 0, stream>>>(
        x, We, be, pre, ws_cand, ws_cnt, cap, features, ws_valsT, ws_idxT);

    // 4) sparse decoder
    decoder_kernel<<<D_MODEL, 1024, 0, stream>>>(
        Wd, bd, ws_valsT, ws_idxT, recon);
}

// Round 19
// 743.040 us; speedup vs baseline: 1.0904x; 1.0560x over previous
//
#include <hip/hip_runtime.h>
#include <cstddef>
#include <cstdint>
#include <cmath>

#define D_MODEL 2048
#define DICT    32768
#define KTOP    32
#define NCAND_FB 96         // fallback hist margin (rank cum >= 96)
#define CAPMAX  256
#define T_OPT   2.70f       // epilogue collect threshold
#define BKT     64                  // K-tile depth (r16 config: best verified)
#define NT_K    (D_MODEL / BKT)     // 32 K-tiles
#define NROWS   2048
#define TMB     (NROWS / 256)       // 8  row tiles
#define TNB     (DICT / 256)        // 128 col tiles

typedef float    f32x4  __attribute__((ext_vector_type(4)));
typedef __bf16   bf16x8 __attribute__((ext_vector_type(8)));
typedef unsigned short us8 __attribute__((ext_vector_type(8)));

__device__ __forceinline__ unsigned short f2bf_rne(float f) {
    unsigned u = __builtin_bit_cast(unsigned, f);
    unsigned r = u + 0x7fffu + ((u >> 16) & 1u);
    return (unsigned short)(r >> 16);
}

__device__ __forceinline__ void gload16(const void* g, const void* s) {
    __builtin_amdgcn_global_load_lds(
        (const __attribute__((address_space(1))) unsigned int*)g,
        (__attribute__((address_space(3))) unsigned int*)s, 16, 0, 0);
}

// ---------------------------------------------------------------------------
// Convert x and We f32 -> bf16, pre-tiled per 256-row tile into 32 K-tiles of
// 64 k; inverse-swizzled source layout (byte ^= (rloc&7)<<4 per 128B line).
// ---------------------------------------------------------------------------
__global__ __launch_bounds__(256) void convert_tiles(
    const float* __restrict__ x,
    const float* __restrict__ We,
    unsigned short* __restrict__ xbf,     // [TMB][NT_K][16384] ushorts
    unsigned short* __restrict__ webf)    // [TNB][NT_K][16384] ushorts
{
    const size_t NX = (size_t)NROWS * 64;
    size_t id = (size_t)blockIdx.x * 256 + threadIdx.x;

    const float* src;
    unsigned short* dstb;
    int row, s;
    if (id < NX) {
        row = (int)(id >> 6); s = (int)(id & 63);
        src = x + (size_t)row * D_MODEL + s * 32;
        dstb = xbf + ((size_t)(row >> 8) * NT_K + (s >> 1)) * 16384
                   + ((row >> 7) & 1) * 8192;
    } else {
        id -= NX;
        row = (int)(id >> 6); s = (int)(id & 63);
        src = We + (size_t)row * D_MODEL + s * 32;
        dstb = webf + ((size_t)(row >> 8) * NT_K + (s >> 1)) * 16384
                    + ((row >> 7) & 1) * 8192;
    }
    const int rloc = row & 127;
    const int koff = (s & 1) * 64;

    #pragma unroll
    for (int qc = 0; qc < 4; ++qc) {
        float4 v0 = reinterpret_cast<const float4*>(src)[qc * 2];
        float4 v1 = reinterpret_cast<const float4*>(src)[qc * 2 + 1];
        us8 c;
        c[0] = f2bf_rne(v0.x); c[1] = f2bf_rne(v0.y);
        c[2] = f2bf_rne(v0.z); c[3] = f2bf_rne(v0.w);
        c[4] = f2bf_rne(v1.x); c[5] = f2bf_rne(v1.y);
        c[6] = f2bf_rne(v1.z); c[7] = f2bf_rne(v1.w);
        const int byteoff = (rloc * 128 + koff + qc * 16) ^ ((rloc & 7) << 4);
        *reinterpret_cast<us8*>(reinterpret_cast<char*>(dstb) + byteoff) = c;
    }
}

// ---------------------------------------------------------------------------
// Encoder GEMM — r16 config (best verified: 375 us, MfmaUtil 31%, 0 bank
// conflicts): 256x256 tile, BK=64, 128KB LDS, r10 deep-pipelined schedule
// (stage u+2 at P3/P4 into [cur], vmcnt(8) retires u+1 exactly — 8 loads in
// flight across the tile boundary). Epilogue: pure store loop + thread-local
// 4-slot collection. [r17/r18 falsified the 2-blocks/CU (BK=32) variant:
// 420-454 us even with conflicts fixed to 0; r11 falsified register
// pipelining. This template family's encoder floor is ~370 us.]
// ---------------------------------------------------------------------------
__global__ __launch_bounds__(512, 2) void encoder_bf16(
    const unsigned short* __restrict__ xbf,
    const unsigned short* __restrict__ webf,
    const float* __restrict__ bias,
    float* __restrict__ C,
    int* __restrict__ cand_idx,           // [NROWS][cap]
    int* __restrict__ cand_cnt,           // [NROWS], pre-zeroed
    int cap)
{
    __shared__ __align__(16) unsigned short Ab[2][2][8192];   // [dbuf][half]
    __shared__ __align__(16) unsigned short Bb[2][2][8192];

    const int t    = threadIdx.x;
    const int lane = t & 63;
    const int w    = t >> 6;        // 0..7
    const int wm   = w >> 2;        // 0..1  (128-row half; = A half index)
    const int wn   = w & 3;         // 0..3  (64-col slice)
    const int hB   = wn >> 1;       // B half index

    const int bid = blockIdx.x;
    const int swz = (bid & 7) * (TMB * TNB / 8) + (bid >> 3);
    const int mt  = swz & (TMB - 1);
    const int nt  = swz >> 3;

    const char* As = (const char*)xbf  + (size_t)mt * (NT_K * 32768);
    const char* Bs = (const char*)webf + (size_t)nt * (NT_K * 32768);

    f32x4 acc[8][4];
    #pragma unroll
    for (int i = 0; i < 8; ++i)
        #pragma unroll
        for (int j = 0; j < 4; ++j) acc[i][j] = (f32x4)0.f;

    const int soff = w * 2048 + lane * 16;   // byte offset in half-tile block
    const int dsti = w * 1024 + lane * 8;    // ushort idx in LDS half-buf

    #define STAGE_A(buf, u, h) do {                                          \
        const char* s_ = As + (size_t)(u) * 32768 + (h) * 16384 + soff;      \
        gload16(s_,        &Ab[buf][h][dsti]);                               \
        gload16(s_ + 1024, &Ab[buf][h][dsti + 512]);                         \
    } while (0)
    #define STAGE_B(buf, u, h) do {                                          \
        const char* s_ = Bs + (size_t)(u) * 32768 + (h) * 16384 + soff;      \
        gload16(s_,        &Bb[buf][h][dsti]);                               \
        gload16(s_ + 1024, &Bb[buf][h][dsti + 512]);                         \
    } while (0)

    bf16x8 a[4][2], b0[2][2], b1[2][2];

    #define LDA(sub) do {                                                    \
        _Pragma("unroll") for (int i = 0; i < 4; ++i)                        \
        _Pragma("unroll") for (int ks = 0; ks < 2; ++ks) {                   \
            const int rl = (sub) * 64 + i * 16 + (lane & 15);                \
            const int by = (rl * 128 + ks * 64 + ((lane >> 4) * 16))         \
                           ^ ((rl & 7) << 4);                                \
            a[i][ks] = __builtin_bit_cast(bf16x8,                            \
                *reinterpret_cast<const us8*>(                               \
                    (const char*)&Ab[cur][wm][0] + by));                     \
        } } while (0)
    #define LDB(breg, q) do {                                                \
        _Pragma("unroll") for (int j = 0; j < 2; ++j)                        \
        _Pragma("unroll") for (int ks = 0; ks < 2; ++ks) {                   \
            const int cl = (wn & 1) * 64 + (q) * 32 + j * 16 + (lane & 15);  \
            const int by = (cl * 128 + ks * 64 + ((lane >> 4) * 16))         \
                           ^ ((cl & 7) << 4);                                \
            breg[j][ks] = __builtin_bit_cast(bf16x8,                         \
                *reinterpret_cast<const us8*>(                               \
                    (const char*)&Bb[cur][hB][0] + by));                     \
        } } while (0)
    #define MMA16(ib, jb, breg) do {                                         \
        _Pragma("unroll") for (int i = 0; i < 4; ++i)                        \
        _Pragma("unroll") for (int j = 0; j < 2; ++j)                        \
        _Pragma("unroll") for (int ks = 0; ks < 2; ++ks)                     \
            acc[(ib) + i][(jb) + j] = __builtin_amdgcn_mfma_f32_16x16x32_bf16( \
                a[i][ks], breg[j][ks], acc[(ib) + i][(jb) + j], 0, 0, 0);    \
    } while (0)

    // prologue: stage tiles 0 and 1 (16 loads); retire tile 0, keep tile 1
    STAGE_B(0, 0, 0); STAGE_B(0, 0, 1);
    STAGE_A(0, 0, 0); STAGE_A(0, 0, 1);
    STAGE_B(1, 1, 0); STAGE_B(1, 1, 1);
    STAGE_A(1, 1, 0); STAGE_A(1, 1, 1);
    asm volatile("s_waitcnt vmcnt(8)" ::: "memory");
    __builtin_amdgcn_sched_barrier(0);
    __builtin_amdgcn_s_barrier();

    int cur = 0;
    for (int u = 0; u < NT_K; ++u) {
        // ---- P1: ld A-sub0 (8) + B-q0 (4)
        LDA(0);
        LDB(b0, 0);
        __builtin_amdgcn_s_barrier();
        asm volatile("s_waitcnt lgkmcnt(0)" ::: "memory");
        __builtin_amdgcn_sched_barrier(0);
        __builtin_amdgcn_s_setprio(1);
        MMA16(0, 0, b0);
        __builtin_amdgcn_s_setprio(0);
        __builtin_amdgcn_s_barrier();

        // ---- P2: ld B-q1 (4)
        LDB(b1, 1);
        __builtin_amdgcn_s_barrier();
        asm volatile("s_waitcnt lgkmcnt(0)" ::: "memory");
        __builtin_amdgcn_sched_barrier(0);
        __builtin_amdgcn_s_setprio(1);
        MMA16(0, 2, b1);
        __builtin_amdgcn_s_setprio(0);
        __builtin_amdgcn_s_barrier();

        // ---- P3: ld A-sub1 (8) || stage B0(u+2) into [cur]
        LDA(1);
        if (u + 2 < NT_K) STAGE_B(cur, u + 2, 0);
        __builtin_amdgcn_s_barrier();
        asm volatile("s_waitcnt lgkmcnt(0)" ::: "memory");
        __builtin_amdgcn_sched_barrier(0);
        __builtin_amdgcn_s_setprio(1);
        MMA16(4, 2, b1);
        __builtin_amdgcn_s_setprio(0);
        __builtin_amdgcn_s_barrier();

        // ---- P4: stage B1/A0/A1(u+2); retire (u+1), keep (u+2)
        if (u + 2 < NT_K) {
            STAGE_B(cur, u + 2, 1);
            STAGE_A(cur, u + 2, 0);
            STAGE_A(cur, u + 2, 1);
            asm volatile("s_waitcnt vmcnt(8)" ::: "memory");
        } else {
            asm volatile("s_waitcnt vmcnt(0)" ::: "memory");
        }
        __builtin_amdgcn_sched_barrier(0);
        __builtin_amdgcn_s_barrier();
        __builtin_amdgcn_s_setprio(1);
        MMA16(4, 0, b0);
        __builtin_amdgcn_s_setprio(0);
        __builtin_amdgcn_s_barrier();

        cur ^= 1;
    }
    #undef STAGE_A
    #undef STAGE_B
    #undef LDA
    #undef LDB
    #undef MMA16

    const int m0 = mt * 256, n0 = nt * 256;
    float bvj[4];
    #pragma unroll
    for (int j = 0; j < 4; ++j)
        bvj[j] = bias[n0 + wn * 64 + j * 16 + (lane & 15)];

    // pure store loop (no branches/atomics)
    #pragma unroll
    for (int j = 0; j < 4; ++j) {
        const int col = n0 + wn * 64 + j * 16 + (lane & 15);
        #pragma unroll
        for (int i = 0; i < 8; ++i) {
            const int rowb = m0 + wm * 128 + i * 16 + ((lane >> 4) * 4);
            #pragma unroll
            for (int r = 0; r < 4; ++r)
                C[(size_t)(rowb + r) * DICT + col] = acc[i][j][r] + bvj[j];
        }
    }

    // collection: thread-local 4-slot compare pass, then short emission.
    int nh = 0, h0 = 0, h1 = 0, h2 = 0, h3 = 0;
    #pragma unroll
    for (int j = 0; j < 4; ++j) {
        const int col = n0 + wn * 64 + j * 16 + (lane & 15);
        #pragma unroll
        for (int i = 0; i < 8; ++i) {
            const int rowb = m0 + wm * 128 + i * 16 + ((lane >> 4) * 4);
            #pragma unroll
            for (int r = 0; r < 4; ++r) {
                if (acc[i][j][r] + bvj[j] >= T_OPT) {
                    const int enc = ((rowb + r) << 15) | col;
                    if      (nh == 0) h0 = enc;
                    else if (nh == 1) h1 = enc;
                    else if (nh == 2) h2 = enc;
                    else if (nh == 3) h3 = enc;
                    else {
                        const int row2 = enc >> 15;
                        const int pos2 = atomicAdd(&cand_cnt[row2], 1);
                        if (pos2 < cap)
                            cand_idx[(size_t)row2 * cap + pos2] = enc & 0x7FFF;
                    }
                    ++nh;
                }
            }
        }
    }
    #pragma unroll
    for (int s2 = 0; s2 < 4; ++s2) {
        if (nh > s2) {
            const int enc = (s2 == 0) ? h0 : (s2 == 1) ? h1
                          : (s2 == 2) ? h2 : h3;
            const int row2 = enc >> 15;
            const int pos  = atomicAdd(&cand_cnt[row2], 1);
            if (pos < cap)
                cand_idx[(size_t)row2 * cap + pos] = enc & 0x7FFF;
        }
    }
}

// ---------------------------------------------------------------------------
// Exact f32 recompute + features-row zeroing + exact top-32 + scatter.
// Three approx bands: skip / sure-in (use approx) / ambiguous (exact dot).
// Fallback hist path for degenerate rows (correctness never depends on T_OPT).
// ---------------------------------------------------------------------------
__global__ __launch_bounds__(256) void recompute_select_kernel(
    const float* __restrict__ x,
    const float* __restrict__ We,
    const float* __restrict__ be,
    const float* __restrict__ pre,
    const int*   __restrict__ cand_idx,
    const int*   __restrict__ cand_cnt,
    int cap,
    float* __restrict__ features,
    float* __restrict__ valsT,           // [KTOP][NROWS]
    int*   __restrict__ idxT)            // [KTOP][NROWS]
{
    __shared__ float xr[D_MODEL];
    __shared__ float cv[CAPMAX];
    __shared__ int   ci[CAPMAX];
    __shared__ float av_s[CAPMAX];
    __shared__ unsigned cnt_part[4];
    __shared__ unsigned hist[2048];
    __shared__ unsigned part[2][256];
    __shared__ int s_thr;
    __shared__ unsigned s_cnt;

    const int n    = blockIdx.x;
    const int t    = threadIdx.x;
    const int lane = t & 63;
    const int w    = t >> 6;
    const int rawcnt = cand_cnt[n];
    int cnt = rawcnt < cap ? rawcnt : cap;

    float4* frow = reinterpret_cast<float4*>(features + (size_t)n * DICT);
    const float4 z4 = make_float4(0.f, 0.f, 0.f, 0.f);
    #pragma unroll 8
    for (int i = t; i < DICT / 4; i += 256) frow[i] = z4;

    for (int i = t; i < D_MODEL / 4; i += 256)
        reinterpret_cast<float4*>(xr)[i] =
            reinterpret_cast<const float4*>(x + (size_t)n * D_MODEL)[i];
    for (int c = t; c < cnt; c += 256) ci[c] = cand_idx[(size_t)n * cap + c];
    __syncthreads();

    float av = -INFINITY;
    if (t < cnt) av = pre[(size_t)n * DICT + ci[t]];
    if (t < CAPMAX) av_s[t] = av;
    __syncthreads();

    float lo = 0.f, hi = 16.f;
    for (int it = 0; it < 18; ++it) {
        const float mid = 0.5f * (lo + hi);
        unsigned long long b = __ballot(av >= mid);
        if (lane == 0) cnt_part[w] = (unsigned)__popcll(b);
        __syncthreads();
        const int c32 = (int)(cnt_part[0] + cnt_part[1] + cnt_part[2] + cnt_part[3]);
        if (c32 >= KTOP) lo = mid; else hi = mid;
        __syncthreads();
    }
    float cutoff  = lo - 0.08f;
    float sure_hi = lo + 0.17f;

    const bool ok = (rawcnt <= cap) && (cnt >= KTOP) && (cutoff >= T_OPT);
    if (!ok) {
        for (int i = t; i < 2048; i += 256) hist[i] = 0;
        if (t == 0) { s_thr = -1; s_cnt = 0; }
        __syncthreads();
        const float4* srcp = reinterpret_cast<const float4*>(pre + (size_t)n * DICT);
        for (int p = 0; p < DICT / 1024; ++p) {
            float4 v = srcp[t + 256 * p];
            float e[4] = {v.x, v.y, v.z, v.w};
            #pragma unroll
            for (int j = 0; j < 4; ++j)
                if (e[j] > 0.f)
                    atomicAdd(&hist[__builtin_bit_cast(unsigned, e[j]) >> 20], 1u);
        }
        __syncthreads();
        unsigned hv[8];
        unsigned local = 0;
        #pragma unroll
        for (int b = 0; b < 8; ++b) { hv[b] = hist[t * 8 + b]; local += hv[b]; }
        part[0][t] = local;
        __syncthreads();
        int sb = 0;
        for (int s = 1; s < 256; s <<= 1) {
            unsigned v2 = part[sb][t];
            if (t + s < 256) v2 += part[sb][t + s];
            part[sb ^ 1][t] = v2;
            sb ^= 1;
            __syncthreads();
        }
        const unsigned above = (t < 255) ? part[sb][t + 1] : 0;
        unsigned cum = above;
        int mybin = -1;
        #pragma unroll
        for (int b = 7; b >= 0; --b) {
            cum += hv[b];
            if (mybin < 0 && cum >= NCAND_FB) mybin = t * 8 + b;
        }
        if (mybin >= 0) atomicMax(&s_thr, mybin);
        __syncthreads();
        const unsigned thrb = (s_thr < 0) ? 0u : (unsigned)s_thr;
        for (int p = 0; p < DICT / 1024; ++p) {
            float4 v = srcp[t + 256 * p];
            float e[4] = {v.x, v.y, v.z, v.w};
            #pragma unroll
            for (int j = 0; j < 4; ++j) {
                if (e[j] > 0.f &&
                    (__builtin_bit_cast(unsigned, e[j]) >> 20) >= thrb) {
                    unsigned pos = atomicAdd(&s_cnt, 1u);
                    if (pos < (unsigned)cap) {
                        ci[pos]   = (t + 256 * p) * 4 + j;
                        av_s[pos] = e[j];
                    }
                }
            }
        }
        __syncthreads();
        cnt = (int)min(s_cnt, (unsigned)cap);
        av = (t < cnt) ? av_s[t] : -INFINITY;
        lo = 0.f; hi = 16.f;
        for (int it = 0; it < 18; ++it) {
            const float mid = 0.5f * (lo + hi);
            unsigned long long b = __ballot(av >= mid);
            if (lane == 0) cnt_part[w] = (unsigned)__popcll(b);
            __syncthreads();
            const int c32 = (int)(cnt_part[0] + cnt_part[1] + cnt_part[2] + cnt_part[3]);
            if (c32 >= KTOP) lo = mid; else hi = mid;
            __syncthreads();
        }
        cutoff  = lo - 0.08f;
        sure_hi = lo + 0.17f;
    }

    for (int c = w; c < cnt; c += 4) {
        const float a_v = av_s[c];
        if (a_v < cutoff)   { if (lane == 0) cv[c] = -INFINITY; continue; }
        if (a_v > sure_hi)  { if (lane == 0) cv[c] = a_v;       continue; }
        const int idx = ci[c];
        const float4* wrow = reinterpret_cast<const float4*>(We + (size_t)idx * D_MODEL);
        const float4* xro  = reinterpret_cast<const float4*>(xr);
        float s = 0.f;
        #pragma unroll
        for (int p = 0; p < 8; ++p) {
            float4 a = xro[lane + 64 * p];
            float4 b = wrow[lane + 64 * p];
            s = fmaf(a.x, b.x, s); s = fmaf(a.y, b.y, s);
            s = fmaf(a.z, b.z, s); s = fmaf(a.w, b.w, s);
        }
        #pragma unroll
        for (int sh = 1; sh < 64; sh <<= 1) s += __shfl_xor(s, sh);
        if (lane == 0) cv[c] = s + be[idx];
    }
    __syncthreads();

    if (w == 0) {
        float pv[CAPMAX / 64];
        int   pi[CAPMAX / 64];
        #pragma unroll
        for (int qq = 0; qq < CAPMAX / 64; ++qq) {
            const int c = lane + 64 * qq;
            const bool okc = c < cnt;
            pv[qq] = okc ? cv[c] : -INFINITY;
            pi[qq] = okc ? ci[c] : 0x7fffffff;
        }
        for (int r = 0; r < KTOP; ++r) {
            float bv = pv[0]; int bi = pi[0]; int bq = 0;
            #pragma unroll
            for (int qq = 1; qq < CAPMAX / 64; ++qq)
                if (pv[qq] > bv || (pv[qq] == bv && pi[qq] < bi)) {
                    bv = pv[qq]; bi = pi[qq]; bq = qq;
                }
            float gv = bv; int gi = bi;
            #pragma unroll
            for (int s = 1; s < 64; s <<= 1) {
                float ov = __shfl_xor(gv, s);
                int   oi = __shfl_xor(gi, s);
                if (ov > gv || (ov == gv && oi < gi)) { gv = ov; gi = oi; }
            }
            if (bi == gi) pv[bq] = -INFINITY;
            if (lane == 0) {
                const bool valid = (gi != 0x7fffffff) && (gv != -INFINITY);
                const float rv = (valid && gv > 0.f) ? gv : 0.f;
                valsT[r * NROWS + n] = rv;
                idxT[r * NROWS + n]  = valid ? gi : 0;
                if (valid) features[(size_t)n * DICT + gi] = rv;
            }
        }
    }
}

// ---------------------------------------------------------------------------
// Decoder: block per d, full Wd row (128KB) in LDS, 1024 threads.
// ---------------------------------------------------------------------------
__global__ __launch_bounds__(1024) void decoder_kernel(
    const float* __restrict__ Wd,
    const float* __restrict__ bd,
    const float* __restrict__ valsT,     // [KTOP][NROWS]
    const int*   __restrict__ idxT,      // [KTOP][NROWS]
    float* __restrict__ recon)
{
    __shared__ float wrow[DICT];         // 128 KB
    const int d = blockIdx.x;
    const int t = threadIdx.x;
    const float* src = Wd + (size_t)d * DICT;

    for (int i = t; i < DICT / 4; i += 1024)
        reinterpret_cast<float4*>(wrow)[i] =
            reinterpret_cast<const float4*>(src)[i];
    __syncthreads();

    const float b = bd[d];
    #pragma unroll
    for (int u = 0; u < NROWS / 1024; ++u) {
        const int n = t + 1024 * u;
        float a0 = 0.f, a1 = 0.f, a2 = 0.f, a3 = 0.f;
        #pragma unroll
        for (int k = 0; k < KTOP; k += 8) {
            float v0 = valsT[(k + 0) * NROWS + n];
            float v1 = valsT[(k + 1) * NROWS + n];
            float v2 = valsT[(k + 2) * NROWS + n];
            float v3 = valsT[(k + 3) * NROWS + n];
            float v4 = valsT[(k + 4) * NROWS + n];
            float v5 = valsT[(k + 5) * NROWS + n];
            float v6 = valsT[(k + 6) * NROWS + n];
            float v7 = valsT[(k + 7) * NROWS + n];
            int i0 = idxT[(k + 0) * NROWS + n];
            int i1 = idxT[(k + 1) * NROWS + n];
            int i2 = idxT[(k + 2) * NROWS + n];
            int i3 = idxT[(k + 3) * NROWS + n];
            int i4 = idxT[(k + 4) * NROWS + n];
            int i5 = idxT[(k + 5) * NROWS + n];
            int i6 = idxT[(k + 6) * NROWS + n];
            int i7 = idxT[(k + 7) * NROWS + n];
            a0 = fmaf(v0, wrow[i0], a0);
            a1 = fmaf(v1, wrow[i1], a1);
            a2 = fmaf(v2, wrow[i2], a2);
            a3 = fmaf(v3, wrow[i3], a3);
            a0 = fmaf(v4, wrow[i4], a0);
            a1 = fmaf(v5, wrow[i5], a1);
            a2 = fmaf(v6, wrow[i6], a2);
            a3 = fmaf(v7, wrow[i7], a3);
        }
        recon[(size_t)n * D_MODEL + d] = ((a0 + a1) + (a2 + a3)) + b;
    }
}

// ---------------------------------------------------------------------------
extern "C" void kernel_launch(void* const* d_in, const int* in_sizes, int n_in,
                              void* d_out, int out_size, void* d_ws, size_t ws_size,
                              hipStream_t stream)
{
    const float* x  = (const float*)d_in[0];
    const float* We = (const float*)d_in[1];
    const float* be = (const float*)d_in[2];
    const float* Wd = (const float*)d_in[3];
    const float* bd = (const float*)d_in[4];

    float* out      = (float*)d_out;
    float* recon    = out;
    float* features = out + (size_t)NROWS * D_MODEL;
    float* pre      = features + (size_t)NROWS * DICT;

    // bf16 tiled operands parked in the features region (overwritten by
    // recompute's per-row zeroing of features)
    unsigned short* webf = (unsigned short*)features;                 // 128 MB
    unsigned short* xbf  = webf + (size_t)TNB * NT_K * 16384;         // + 8 MB

    long cap_l = (long)(ws_size / 4 - (size_t)NROWS * (1 + 2 * KTOP)) / NROWS;
    int cap = (int)(cap_l < 64 ? 64 : (cap_l > CAPMAX ? CAPMAX : cap_l));

    char* ws = (char*)d_ws;
    int*   ws_cand  = (int*)ws;
    int*   ws_cnt   = (int*)(ws + (size_t)NROWS * cap * 4);
    float* ws_valsT = (float*)(ws + (size_t)NROWS * (cap + 1) * 4);
    int*   ws_idxT  = (int*)(ws + (size_t)NROWS * (cap + 1 + KTOP) * 4);

    // 0) zero per-row candidate counters
    hipMemsetAsync(ws_cnt, 0, (size_t)NROWS * sizeof(int), stream);

    // 1) convert + tile + swizzle operands to bf16
    const int conv_blocks = (int)(((size_t)NROWS * 64 + (size_t)DICT * 64) / 256);
    convert_tiles<<<conv_blocks, 256, 0, stream>>>(x, We, xbf, webf);

    // 2) encoder GEMM -> approx pre_acts + fused candidate collection
    encoder_bf16<<<TMB * TNB, 512, 0, stream>>>(
        xbf, webf, be, pre, ws_cand, ws_cnt, cap);

    // 3) banded exact recompute + features zeroing + top-32 + scatter
    recompute_select_kernel<<<NROWS, 256, 0, stream>>>(
        x, We, be, pre, ws_cand, ws_cnt, cap, features, ws_valsT, ws_idxT);

    // 4) sparse decoder
    decoder_kernel<<<D_MODEL, 1024, 0, stream>>>(
        Wd, bd, ws_valsT, ws_idxT, recon);
}

// Round 20
// 724.214 us; speedup vs baseline: 1.1188x; 1.0260x over previous
//
#include <hip/hip_runtime.h>
#include <cstddef>
#include <cstdint>
#include <cmath>

#define D_MODEL 2048
#define DICT    32768
#define KTOP    32
#define NCAND_FB 96         // fallback hist margin (rank cum >= 96)
#define CAPMAX  256
#define T_OPT   2.70f       // epilogue collect threshold
#define BKT     64                  // K-tile depth
#define NT_K    (D_MODEL / BKT)     // 32 K-tiles
#define NROWS   2048
#define TMB     (NROWS / 256)       // 8  row tiles
#define TNB     (DICT / 256)        // 128 col tiles

typedef float    f32x4  __attribute__((ext_vector_type(4)));
typedef __bf16   bf16x8 __attribute__((ext_vector_type(8)));
typedef unsigned short us8 __attribute__((ext_vector_type(8)));

__device__ __forceinline__ unsigned short f2bf_rne(float f) {
    unsigned u = __builtin_bit_cast(unsigned, f);
    unsigned r = u + 0x7fffu + ((u >> 16) & 1u);
    return (unsigned short)(r >> 16);
}

__device__ __forceinline__ void gload16(const void* g, const void* s) {
    __builtin_amdgcn_global_load_lds(
        (const __attribute__((address_space(1))) unsigned int*)g,
        (__attribute__((address_space(3))) unsigned int*)s, 16, 0, 0);
}

// ---------------------------------------------------------------------------
// Convert x and We f32 -> bf16, pre-tiled per 256-row tile into 32 K-tiles of
// 64 k; inverse-swizzled source layout (byte ^= (rloc&7)<<4 per 128B line).
// ---------------------------------------------------------------------------
__global__ __launch_bounds__(256) void convert_tiles(
    const float* __restrict__ x,
    const float* __restrict__ We,
    unsigned short* __restrict__ xbf,     // [TMB][NT_K][16384] ushorts
    unsigned short* __restrict__ webf)    // [TNB][NT_K][16384] ushorts
{
    const size_t NX = (size_t)NROWS * 64;
    size_t id = (size_t)blockIdx.x * 256 + threadIdx.x;

    const float* src;
    unsigned short* dstb;
    int row, s;
    if (id < NX) {
        row = (int)(id >> 6); s = (int)(id & 63);
        src = x + (size_t)row * D_MODEL + s * 32;
        dstb = xbf + ((size_t)(row >> 8) * NT_K + (s >> 1)) * 16384
                   + ((row >> 7) & 1) * 8192;
    } else {
        id -= NX;
        row = (int)(id >> 6); s = (int)(id & 63);
        src = We + (size_t)row * D_MODEL + s * 32;
        dstb = webf + ((size_t)(row >> 8) * NT_K + (s >> 1)) * 16384
                    + ((row >> 7) & 1) * 8192;
    }
    const int rloc = row & 127;
    const int koff = (s & 1) * 64;

    #pragma unroll
    for (int qc = 0; qc < 4; ++qc) {
        float4 v0 = reinterpret_cast<const float4*>(src)[qc * 2];
        float4 v1 = reinterpret_cast<const float4*>(src)[qc * 2 + 1];
        us8 c;
        c[0] = f2bf_rne(v0.x); c[1] = f2bf_rne(v0.y);
        c[2] = f2bf_rne(v0.z); c[3] = f2bf_rne(v0.w);
        c[4] = f2bf_rne(v1.x); c[5] = f2bf_rne(v1.y);
        c[6] = f2bf_rne(v1.z); c[7] = f2bf_rne(v1.w);
        const int byteoff = (rloc * 128 + koff + qc * 16) ^ ((rloc & 7) << 4);
        *reinterpret_cast<us8*>(reinterpret_cast<char*>(dstb) + byteoff) = c;
    }
}

// ---------------------------------------------------------------------------
// Encoder GEMM — r16 geometry + r20 scheduling change: the per-phase explicit
// lgkmcnt(0)+sched_barrier drains are REMOVED. They forced a full LDS drain
// (~1150 cyc at P1) before any MFMA issued — reads and MFMA summed, never
// overlapped (measured 7030 cyc/K-tile vs 2800 ideal). hipcc emits
// fine-grained per-MFMA lgkmcnt waits (m97 asm evidence), interleaving read
// completion with MFMA issue. Kept: all barriers, the full vmcnt(8) ledger
// (compiler can't connect gload_lds->ds_read), setprio, one lgkmcnt(0)
// before P4's A-stage (buffer-recycle safety; free, as P3's MFMAs already
// consumed those reads). B-stages moved to P3 (readers drained by P1/P2's
// compiler waits + barriers). Ledger unchanged: vmcnt(8) retires u+1 exactly.
// ---------------------------------------------------------------------------
__global__ __launch_bounds__(512, 2) void encoder_bf16(
    const unsigned short* __restrict__ xbf,
    const unsigned short* __restrict__ webf,
    const float* __restrict__ bias,
    float* __restrict__ C,
    int* __restrict__ cand_idx,           // [NROWS][cap]
    int* __restrict__ cand_cnt,           // [NROWS], pre-zeroed
    int cap)
{
    __shared__ __align__(16) unsigned short Ab[2][2][8192];   // [dbuf][half]
    __shared__ __align__(16) unsigned short Bb[2][2][8192];

    const int t    = threadIdx.x;
    const int lane = t & 63;
    const int w    = t >> 6;        // 0..7
    const int wm   = w >> 2;        // 0..1  (128-row half; = A half index)
    const int wn   = w & 3;         // 0..3  (64-col slice)
    const int hB   = wn >> 1;       // B half index

    const int bid = blockIdx.x;
    const int swz = (bid & 7) * (TMB * TNB / 8) + (bid >> 3);
    const int mt  = swz & (TMB - 1);
    const int nt  = swz >> 3;

    const char* As = (const char*)xbf  + (size_t)mt * (NT_K * 32768);
    const char* Bs = (const char*)webf + (size_t)nt * (NT_K * 32768);

    f32x4 acc[8][4];
    #pragma unroll
    for (int i = 0; i < 8; ++i)
        #pragma unroll
        for (int j = 0; j < 4; ++j) acc[i][j] = (f32x4)0.f;

    const int soff = w * 2048 + lane * 16;   // byte offset in half-tile block
    const int dsti = w * 1024 + lane * 8;    // ushort idx in LDS half-buf

    #define STAGE_A(buf, u, h) do {                                          \
        const char* s_ = As + (size_t)(u) * 32768 + (h) * 16384 + soff;      \
        gload16(s_,        &Ab[buf][h][dsti]);                               \
        gload16(s_ + 1024, &Ab[buf][h][dsti + 512]);                         \
    } while (0)
    #define STAGE_B(buf, u, h) do {                                          \
        const char* s_ = Bs + (size_t)(u) * 32768 + (h) * 16384 + soff;      \
        gload16(s_,        &Bb[buf][h][dsti]);                               \
        gload16(s_ + 1024, &Bb[buf][h][dsti + 512]);                         \
    } while (0)

    bf16x8 a[4][2], b0[2][2], b1[2][2];

    #define LDA(sub) do {                                                    \
        _Pragma("unroll") for (int i = 0; i < 4; ++i)                        \
        _Pragma("unroll") for (int ks = 0; ks < 2; ++ks) {                   \
            const int rl = (sub) * 64 + i * 16 + (lane & 15);                \
            const int by = (rl * 128 + ks * 64 + ((lane >> 4) * 16))         \
                           ^ ((rl & 7) << 4);                                \
            a[i][ks] = __builtin_bit_cast(bf16x8,                            \
                *reinterpret_cast<const us8*>(                               \
                    (const char*)&Ab[cur][wm][0] + by));                     \
        } } while (0)
    #define LDB(breg, q) do {                                                \
        _Pragma("unroll") for (int j = 0; j < 2; ++j)                        \
        _Pragma("unroll") for (int ks = 0; ks < 2; ++ks) {                   \
            const int cl = (wn & 1) * 64 + (q) * 32 + j * 16 + (lane & 15);  \
            const int by = (cl * 128 + ks * 64 + ((lane >> 4) * 16))         \
                           ^ ((cl & 7) << 4);                                \
            breg[j][ks] = __builtin_bit_cast(bf16x8,                         \
                *reinterpret_cast<const us8*>(                               \
                    (const char*)&Bb[cur][hB][0] + by));                     \
        } } while (0)
    #define MMA16(ib, jb, breg) do {                                         \
        _Pragma("unroll") for (int i = 0; i < 4; ++i)                        \
        _Pragma("unroll") for (int j = 0; j < 2; ++j)                        \
        _Pragma("unroll") for (int ks = 0; ks < 2; ++ks)                     \
            acc[(ib) + i][(jb) + j] = __builtin_amdgcn_mfma_f32_16x16x32_bf16( \
                a[i][ks], breg[j][ks], acc[(ib) + i][(jb) + j], 0, 0, 0);    \
    } while (0)

    // prologue: stage tiles 0 and 1 (16 loads); retire tile 0, keep tile 1
    STAGE_B(0, 0, 0); STAGE_B(0, 0, 1);
    STAGE_A(0, 0, 0); STAGE_A(0, 0, 1);
    STAGE_B(1, 1, 0); STAGE_B(1, 1, 1);
    STAGE_A(1, 1, 0); STAGE_A(1, 1, 1);
    asm volatile("s_waitcnt vmcnt(8)" ::: "memory");
    __builtin_amdgcn_sched_barrier(0);
    __builtin_amdgcn_s_barrier();

    int cur = 0;
    for (int u = 0; u < NT_K; ++u) {
        // ---- P1: ld B-q0 then A-sub0 (first-consumed first); compiler
        //          inserts fine-grained lgkm waits inside the MFMA cluster
        LDB(b0, 0);
        LDA(0);
        __builtin_amdgcn_s_barrier();
        __builtin_amdgcn_s_setprio(1);
        MMA16(0, 0, b0);
        __builtin_amdgcn_s_setprio(0);
        __builtin_amdgcn_s_barrier();

        // ---- P2: ld B-q1
        LDB(b1, 1);
        __builtin_amdgcn_s_barrier();
        __builtin_amdgcn_s_setprio(1);
        MMA16(0, 2, b1);
        __builtin_amdgcn_s_setprio(0);
        __builtin_amdgcn_s_barrier();

        // ---- P3: stage both B halves (u+2) into [cur] (readers drained in
        //          P1/P2) || ld A-sub1
        __builtin_amdgcn_sched_barrier(0);
        if (u + 2 < NT_K) { STAGE_B(cur, u + 2, 0); STAGE_B(cur, u + 2, 1); }
        LDA(1);
        __builtin_amdgcn_s_barrier();
        __builtin_amdgcn_s_setprio(1);
        MMA16(4, 2, b1);
        __builtin_amdgcn_s_setprio(0);
        __builtin_amdgcn_s_barrier();

        // ---- P4: drain lgkm (free: P3's MFMAs consumed LDA(1)); stage A
        //          halves (u+2); counted vmcnt retires u+1, keeps u+2
        asm volatile("s_waitcnt lgkmcnt(0)" ::: "memory");
        __builtin_amdgcn_sched_barrier(0);
        if (u + 2 < NT_K) {
            STAGE_A(cur, u + 2, 0);
            STAGE_A(cur, u + 2, 1);
            asm volatile("s_waitcnt vmcnt(8)" ::: "memory");
        } else {
            asm volatile("s_waitcnt vmcnt(0)" ::: "memory");
        }
        __builtin_amdgcn_sched_barrier(0);
        __builtin_amdgcn_s_barrier();
        __builtin_amdgcn_s_setprio(1);
        MMA16(4, 0, b0);
        __builtin_amdgcn_s_setprio(0);
        __builtin_amdgcn_s_barrier();

        cur ^= 1;
    }
    #undef STAGE_A
    #undef STAGE_B
    #undef LDA
    #undef LDB
    #undef MMA16

    const int m0 = mt * 256, n0 = nt * 256;
    float bvj[4];
    #pragma unroll
    for (int j = 0; j < 4; ++j)
        bvj[j] = bias[n0 + wn * 64 + j * 16 + (lane & 15)];

    // pure store loop (no branches/atomics)
    #pragma unroll
    for (int j = 0; j < 4; ++j) {
        const int col = n0 + wn * 64 + j * 16 + (lane & 15);
        #pragma unroll
        for (int i = 0; i < 8; ++i) {
            const int rowb = m0 + wm * 128 + i * 16 + ((lane >> 4) * 4);
            #pragma unroll
            for (int r = 0; r < 4; ++r)
                C[(size_t)(rowb + r) * DICT + col] = acc[i][j][r] + bvj[j];
        }
    }

    // collection: thread-local 4-slot compare pass, then short emission.
    int nh = 0, h0 = 0, h1 = 0, h2 = 0, h3 = 0;
    #pragma unroll
    for (int j = 0; j < 4; ++j) {
        const int col = n0 + wn * 64 + j * 16 + (lane & 15);
        #pragma unroll
        for (int i = 0; i < 8; ++i) {
            const int rowb = m0 + wm * 128 + i * 16 + ((lane >> 4) * 4);
            #pragma unroll
            for (int r = 0; r < 4; ++r) {
                if (acc[i][j][r] + bvj[j] >= T_OPT) {
                    const int enc = ((rowb + r) << 15) | col;
                    if      (nh == 0) h0 = enc;
                    else if (nh == 1) h1 = enc;
                    else if (nh == 2) h2 = enc;
                    else if (nh == 3) h3 = enc;
                    else {
                        const int row2 = enc >> 15;
                        const int pos2 = atomicAdd(&cand_cnt[row2], 1);
                        if (pos2 < cap)
                            cand_idx[(size_t)row2 * cap + pos2] = enc & 0x7FFF;
                    }
                    ++nh;
                }
            }
        }
    }
    #pragma unroll
    for (int s2 = 0; s2 < 4; ++s2) {
        if (nh > s2) {
            const int enc = (s2 == 0) ? h0 : (s2 == 1) ? h1
                          : (s2 == 2) ? h2 : h3;
            const int row2 = enc >> 15;
            const int pos  = atomicAdd(&cand_cnt[row2], 1);
            if (pos < cap)
                cand_idx[(size_t)row2 * cap + pos] = enc & 0x7FFF;
        }
    }
}

// ---------------------------------------------------------------------------
// Exact f32 recompute + features-row zeroing + exact top-32 + scatter.
// Three approx bands: skip / sure-in (use approx) / ambiguous (exact dot).
// Fallback hist path for degenerate rows (correctness never depends on T_OPT).
// ---------------------------------------------------------------------------
__global__ __launch_bounds__(256) void recompute_select_kernel(
    const float* __restrict__ x,
    const float* __restrict__ We,
    const float* __restrict__ be,
    const float* __restrict__ pre,
    const int*   __restrict__ cand_idx,
    const int*   __restrict__ cand_cnt,
    int cap,
    float* __restrict__ features,
    float* __restrict__ valsT,           // [KTOP][NROWS]
    int*   __restrict__ idxT)            // [KTOP][NROWS]
{
    __shared__ float xr[D_MODEL];
    __shared__ float cv[CAPMAX];
    __shared__ int   ci[CAPMAX];
    __shared__ float av_s[CAPMAX];
    __shared__ unsigned cnt_part[4];
    __shared__ unsigned hist[2048];
    __shared__ unsigned part[2][256];
    __shared__ int s_thr;
    __shared__ unsigned s_cnt;

    const int n    = blockIdx.x;
    const int t    = threadIdx.x;
    const int lane = t & 63;
    const int w    = t >> 6;
    const int rawcnt = cand_cnt[n];
    int cnt = rawcnt < cap ? rawcnt : cap;

    float4* frow = reinterpret_cast<float4*>(features + (size_t)n * DICT);
    const float4 z4 = make_float4(0.f, 0.f, 0.f, 0.f);
    #pragma unroll 8
    for (int i = t; i < DICT / 4; i += 256) frow[i] = z4;

    for (int i = t; i < D_MODEL / 4; i += 256)
        reinterpret_cast<float4*>(xr)[i] =
            reinterpret_cast<const float4*>(x + (size_t)n * D_MODEL)[i];
    for (int c = t; c < cnt; c += 256) ci[c] = cand_idx[(size_t)n * cap + c];
    __syncthreads();

    float av = -INFINITY;
    if (t < cnt) av = pre[(size_t)n * DICT + ci[t]];
    if (t < CAPMAX) av_s[t] = av;
    __syncthreads();

    float lo = 0.f, hi = 16.f;
    for (int it = 0; it < 18; ++it) {
        const float mid = 0.5f * (lo + hi);
        unsigned long long b = __ballot(av >= mid);
        if (lane == 0) cnt_part[w] = (unsigned)__popcll(b);
        __syncthreads();
        const int c32 = (int)(cnt_part[0] + cnt_part[1] + cnt_part[2] + cnt_part[3]);
        if (c32 >= KTOP) lo = mid; else hi = mid;
        __syncthreads();
    }
    float cutoff  = lo - 0.08f;
    float sure_hi = lo + 0.17f;

    const bool ok = (rawcnt <= cap) && (cnt >= KTOP) && (cutoff >= T_OPT);
    if (!ok) {
        for (int i = t; i < 2048; i += 256) hist[i] = 0;
        if (t == 0) { s_thr = -1; s_cnt = 0; }
        __syncthreads();
        const float4* srcp = reinterpret_cast<const float4*>(pre + (size_t)n * DICT);
        for (int p = 0; p < DICT / 1024; ++p) {
            float4 v = srcp[t + 256 * p];
            float e[4] = {v.x, v.y, v.z, v.w};
            #pragma unroll
            for (int j = 0; j < 4; ++j)
                if (e[j] > 0.f)
                    atomicAdd(&hist[__builtin_bit_cast(unsigned, e[j]) >> 20], 1u);
        }
        __syncthreads();
        unsigned hv[8];
        unsigned local = 0;
        #pragma unroll
        for (int b = 0; b < 8; ++b) { hv[b] = hist[t * 8 + b]; local += hv[b]; }
        part[0][t] = local;
        __syncthreads();
        int sb = 0;
        for (int s = 1; s < 256; s <<= 1) {
            unsigned v2 = part[sb][t];
            if (t + s < 256) v2 += part[sb][t + s];
            part[sb ^ 1][t] = v2;
            sb ^= 1;
            __syncthreads();
        }
        const unsigned above = (t < 255) ? part[sb][t + 1] : 0;
        unsigned cum = above;
        int mybin = -1;
        #pragma unroll
        for (int b = 7; b >= 0; --b) {
            cum += hv[b];
            if (mybin < 0 && cum >= NCAND_FB) mybin = t * 8 + b;
        }
        if (mybin >= 0) atomicMax(&s_thr, mybin);
        __syncthreads();
        const unsigned thrb = (s_thr < 0) ? 0u : (unsigned)s_thr;
        for (int p = 0; p < DICT / 1024; ++p) {
            float4 v = srcp[t + 256 * p];
            float e[4] = {v.x, v.y, v.z, v.w};
            #pragma unroll
            for (int j = 0; j < 4; ++j) {
                if (e[j] > 0.f &&
                    (__builtin_bit_cast(unsigned, e[j]) >> 20) >= thrb) {
                    unsigned pos = atomicAdd(&s_cnt, 1u);
                    if (pos < (unsigned)cap) {
                        ci[pos]   = (t + 256 * p) * 4 + j;
                        av_s[pos] = e[j];
                    }
                }
            }
        }
        __syncthreads();
        cnt = (int)min(s_cnt, (unsigned)cap);
        av = (t < cnt) ? av_s[t] : -INFINITY;
        lo = 0.f; hi = 16.f;
        for (int it = 0; it < 18; ++it) {
            const float mid = 0.5f * (lo + hi);
            unsigned long long b = __ballot(av >= mid);
            if (lane == 0) cnt_part[w] = (unsigned)__popcll(b);
            __syncthreads();
            const int c32 = (int)(cnt_part[0] + cnt_part[1] + cnt_part[2] + cnt_part[3]);
            if (c32 >= KTOP) lo = mid; else hi = mid;
            __syncthreads();
        }
        cutoff  = lo - 0.08f;
        sure_hi = lo + 0.17f;
    }

    for (int c = w; c < cnt; c += 4) {
        const float a_v = av_s[c];
        if (a_v < cutoff)   { if (lane == 0) cv[c] = -INFINITY; continue; }
        if (a_v > sure_hi)  { if (lane == 0) cv[c] = a_v;       continue; }
        const int idx = ci[c];
        const float4* wrow = reinterpret_cast<const float4*>(We + (size_t)idx * D_MODEL);
        const float4* xro  = reinterpret_cast<const float4*>(xr);
        float s = 0.f;
        #pragma unroll
        for (int p = 0; p < 8; ++p) {
            float4 a = xro[lane + 64 * p];
            float4 b = wrow[lane + 64 * p];
            s = fmaf(a.x, b.x, s); s = fmaf(a.y, b.y, s);
            s = fmaf(a.z, b.z, s); s = fmaf(a.w, b.w, s);
        }
        #pragma unroll
        for (int sh = 1; sh < 64; sh <<= 1) s += __shfl_xor(s, sh);
        if (lane == 0) cv[c] = s + be[idx];
    }
    __syncthreads();

    if (w == 0) {
        float pv[CAPMAX / 64];
        int   pi[CAPMAX / 64];
        #pragma unroll
        for (int qq = 0; qq < CAPMAX / 64; ++qq) {
            const int c = lane + 64 * qq;
            const bool okc = c < cnt;
            pv[qq] = okc ? cv[c] : -INFINITY;
            pi[qq] = okc ? ci[c] : 0x7fffffff;
        }
        for (int r = 0; r < KTOP; ++r) {
            float bv = pv[0]; int bi = pi[0]; int bq = 0;
            #pragma unroll
            for (int qq = 1; qq < CAPMAX / 64; ++qq)
                if (pv[qq] > bv || (pv[qq] == bv && pi[qq] < bi)) {
                    bv = pv[qq]; bi = pi[qq]; bq = qq;
                }
            float gv = bv; int gi = bi;
            #pragma unroll
            for (int s = 1; s < 64; s <<= 1) {
                float ov = __shfl_xor(gv, s);
                int   oi = __shfl_xor(gi, s);
                if (ov > gv || (ov == gv && oi < gi)) { gv = ov; gi = oi; }
            }
            if (bi == gi) pv[bq] = -INFINITY;
            if (lane == 0) {
                const bool valid = (gi != 0x7fffffff) && (gv != -INFINITY);
                const float rv = (valid && gv > 0.f) ? gv : 0.f;
                valsT[r * NROWS + n] = rv;
                idxT[r * NROWS + n]  = valid ? gi : 0;
                if (valid) features[(size_t)n * DICT + gi] = rv;
            }
        }
    }
}

// ---------------------------------------------------------------------------
// Decoder: block per d, full Wd row (128KB) in LDS, 1024 threads.
// ---------------------------------------------------------------------------
__global__ __launch_bounds__(1024) void decoder_kernel(
    const float* __restrict__ Wd,
    const float* __restrict__ bd,
    const float* __restrict__ valsT,     // [KTOP][NROWS]
    const int*   __restrict__ idxT,      // [KTOP][NROWS]
    float* __restrict__ recon)
{
    __shared__ float wrow[DICT];         // 128 KB
    const int d = blockIdx.x;
    const int t = threadIdx.x;
    const float* src = Wd + (size_t)d * DICT;

    for (int i = t; i < DICT / 4; i += 1024)
        reinterpret_cast<float4*>(wrow)[i] =
            reinterpret_cast<const float4*>(src)[i];
    __syncthreads();

    const float b = bd[d];
    #pragma unroll
    for (int u = 0; u < NROWS / 1024; ++u) {
        const int n = t + 1024 * u;
        float a0 = 0.f, a1 = 0.f, a2 = 0.f, a3 = 0.f;
        #pragma unroll
        for (int k = 0; k < KTOP; k += 8) {
            float v0 = valsT[(k + 0) * NROWS + n];
            float v1 = valsT[(k + 1) * NROWS + n];
            float v2 = valsT[(k + 2) * NROWS + n];
            float v3 = valsT[(k + 3) * NROWS + n];
            float v4 = valsT[(k + 4) * NROWS + n];
            float v5 = valsT[(k + 5) * NROWS + n];
            float v6 = valsT[(k + 6) * NROWS + n];
            float v7 = valsT[(k + 7) * NROWS + n];
            int i0 = idxT[(k + 0) * NROWS + n];
            int i1 = idxT[(k + 1) * NROWS + n];
            int i2 = idxT[(k + 2) * NROWS + n];
            int i3 = idxT[(k + 3) * NROWS + n];
            int i4 = idxT[(k + 4) * NROWS + n];
            int i5 = idxT[(k + 5) * NROWS + n];
            int i6 = idxT[(k + 6) * NROWS + n];
            int i7 = idxT[(k + 7) * NROWS + n];
            a0 = fmaf(v0, wrow[i0], a0);
            a1 = fmaf(v1, wrow[i1], a1);
            a2 = fmaf(v2, wrow[i2], a2);
            a3 = fmaf(v3, wrow[i3], a3);
            a0 = fmaf(v4, wrow[i4], a0);
            a1 = fmaf(v5, wrow[i5], a1);
            a2 = fmaf(v6, wrow[i6], a2);
            a3 = fmaf(v7, wrow[i7], a3);
        }
        recon[(size_t)n * D_MODEL + d] = ((a0 + a1) + (a2 + a3)) + b;
    }
}

// ---------------------------------------------------------------------------
extern "C" void kernel_launch(void* const* d_in, const int* in_sizes, int n_in,
                              void* d_out, int out_size, void* d_ws, size_t ws_size,
                              hipStream_t stream)
{
    const float* x  = (const float*)d_in[0];
    const float* We = (const float*)d_in[1];
    const float* be = (const float*)d_in[2];
    const float* Wd = (const float*)d_in[3];
    const float* bd = (const float*)d_in[4];

    float* out      = (float*)d_out;
    float* recon    = out;
    float* features = out + (size_t)NROWS * D_MODEL;
    float* pre      = features + (size_t)NROWS * DICT;

    // bf16 tiled operands parked in the features region (overwritten by
    // recompute's per-row zeroing of features)
    unsigned short* webf = (unsigned short*)features;                 // 128 MB
    unsigned short* xbf  = webf + (size_t)TNB * NT_K * 16384;         // + 8 MB

    long cap_l = (long)(ws_size / 4 - (size_t)NROWS * (1 + 2 * KTOP)) / NROWS;
    int cap = (int)(cap_l < 64 ? 64 : (cap_l > CAPMAX ? CAPMAX : cap_l));

    char* ws = (char*)d_ws;
    int*   ws_cand  = (int*)ws;
    int*   ws_cnt   = (int*)(ws + (size_t)NROWS * cap * 4);
    float* ws_valsT = (float*)(ws + (size_t)NROWS * (cap + 1) * 4);
    int*   ws_idxT  = (int*)(ws + (size_t)NROWS * (cap + 1 + KTOP) * 4);

    // 0) zero per-row candidate counters
    hipMemsetAsync(ws_cnt, 0, (size_t)NROWS * sizeof(int), stream);

    // 1) convert + tile + swizzle operands to bf16
    const int conv_blocks = (int)(((size_t)NROWS * 64 + (size_t)DICT * 64) / 256);
    convert_tiles<<<conv_blocks, 256, 0, stream>>>(x, We, xbf, webf);

    // 2) encoder GEMM -> approx pre_acts + fused candidate collection
    encoder_bf16<<<TMB * TNB, 512, 0, stream>>>(
        xbf, webf, be, pre, ws_cand, ws_cnt, cap);

    // 3) banded exact recompute + features zeroing + top-32 + scatter
    recompute_select_kernel<<<NROWS, 256, 0, stream>>>(
        x, We, be, pre, ws_cand, ws_cnt, cap, features, ws_valsT, ws_idxT);

    // 4) sparse decoder
    decoder_kernel<<<D_MODEL, 1024, 0, stream>>>(
        Wd, bd, ws_valsT, ws_idxT, recon);
}

// Round 21
// 713.849 us; speedup vs baseline: 1.1350x; 1.0145x over previous
//
#include <hip/hip_runtime.h>
#include <cstddef>
#include <cstdint>
#include <cmath>

#define D_MODEL 2048
#define DICT    32768
#define KTOP    32
#define NCAND_FB 96         // fallback hist margin (rank cum >= 96)
#define CAPMAX  256
#define T_OPT   2.70f       // epilogue collect threshold
#define BKT     64                  // K-tile depth
#define NT_K    (D_MODEL / BKT)     // 32 K-tiles
#define NROWS   2048
#define TMB     (NROWS / 256)       // 8  row tiles
#define TNB     (DICT / 256)        // 128 col tiles

typedef float    f32x4  __attribute__((ext_vector_type(4)));
typedef __bf16   bf16x8 __attribute__((ext_vector_type(8)));
typedef unsigned short us8 __attribute__((ext_vector_type(8)));

__device__ __forceinline__ unsigned short f2bf_rne(float f) {
    unsigned u = __builtin_bit_cast(unsigned, f);
    unsigned r = u + 0x7fffu + ((u >> 16) & 1u);
    return (unsigned short)(r >> 16);
}

__device__ __forceinline__ void gload16(const void* g, const void* s) {
    __builtin_amdgcn_global_load_lds(
        (const __attribute__((address_space(1))) unsigned int*)g,
        (__attribute__((address_space(3))) unsigned int*)s, 16, 0, 0);
}

// ---------------------------------------------------------------------------
// Convert x and We f32 -> bf16, pre-tiled per 256-row tile into 32 K-tiles of
// 64 k; inverse-swizzled source layout (byte ^= (rloc&7)<<4 per 128B line).
// ---------------------------------------------------------------------------
__global__ __launch_bounds__(256) void convert_tiles(
    const float* __restrict__ x,
    const float* __restrict__ We,
    unsigned short* __restrict__ xbf,     // [TMB][NT_K][16384] ushorts
    unsigned short* __restrict__ webf)    // [TNB][NT_K][16384] ushorts
{
    const size_t NX = (size_t)NROWS * 64;
    size_t id = (size_t)blockIdx.x * 256 + threadIdx.x;

    const float* src;
    unsigned short* dstb;
    int row, s;
    if (id < NX) {
        row = (int)(id >> 6); s = (int)(id & 63);
        src = x + (size_t)row * D_MODEL + s * 32;
        dstb = xbf + ((size_t)(row >> 8) * NT_K + (s >> 1)) * 16384
                   + ((row >> 7) & 1) * 8192;
    } else {
        id -= NX;
        row = (int)(id >> 6); s = (int)(id & 63);
        src = We + (size_t)row * D_MODEL + s * 32;
        dstb = webf + ((size_t)(row >> 8) * NT_K + (s >> 1)) * 16384
                    + ((row >> 7) & 1) * 8192;
    }
    const int rloc = row & 127;
    const int koff = (s & 1) * 64;

    #pragma unroll
    for (int qc = 0; qc < 4; ++qc) {
        float4 v0 = reinterpret_cast<const float4*>(src)[qc * 2];
        float4 v1 = reinterpret_cast<const float4*>(src)[qc * 2 + 1];
        us8 c;
        c[0] = f2bf_rne(v0.x); c[1] = f2bf_rne(v0.y);
        c[2] = f2bf_rne(v0.z); c[3] = f2bf_rne(v0.w);
        c[4] = f2bf_rne(v1.x); c[5] = f2bf_rne(v1.y);
        c[6] = f2bf_rne(v1.z); c[7] = f2bf_rne(v1.w);
        const int byteoff = (rloc * 128 + koff + qc * 16) ^ ((rloc & 7) << 4);
        *reinterpret_cast<us8*>(reinterpret_cast<char*>(dstb) + byteoff) = c;
    }
}

// ---------------------------------------------------------------------------
// Encoder GEMM — r20 config (best verified: 358 us, MfmaUtil 33%, 0 bank
// conflicts): 256x256 tile, BK=64, deep vmcnt(8) pipeline, compiler-managed
// lgkm waits, fused candidate collection (4-slot + atomics).
// ---------------------------------------------------------------------------
__global__ __launch_bounds__(512, 2) void encoder_bf16(
    const unsigned short* __restrict__ xbf,
    const unsigned short* __restrict__ webf,
    const float* __restrict__ bias,
    float* __restrict__ C,
    int* __restrict__ cand_idx,           // [NROWS][cap]
    int* __restrict__ cand_cnt,           // [NROWS], pre-zeroed
    int cap)
{
    __shared__ __align__(16) unsigned short Ab[2][2][8192];   // [dbuf][half]
    __shared__ __align__(16) unsigned short Bb[2][2][8192];

    const int t    = threadIdx.x;
    const int lane = t & 63;
    const int w    = t >> 6;        // 0..7
    const int wm   = w >> 2;        // 0..1  (128-row half; = A half index)
    const int wn   = w & 3;         // 0..3  (64-col slice)
    const int hB   = wn >> 1;       // B half index

    const int bid = blockIdx.x;
    const int swz = (bid & 7) * (TMB * TNB / 8) + (bid >> 3);
    const int mt  = swz & (TMB - 1);
    const int nt  = swz >> 3;

    const char* As = (const char*)xbf  + (size_t)mt * (NT_K * 32768);
    const char* Bs = (const char*)webf + (size_t)nt * (NT_K * 32768);

    f32x4 acc[8][4];
    #pragma unroll
    for (int i = 0; i < 8; ++i)
        #pragma unroll
        for (int j = 0; j < 4; ++j) acc[i][j] = (f32x4)0.f;

    const int soff = w * 2048 + lane * 16;   // byte offset in half-tile block
    const int dsti = w * 1024 + lane * 8;    // ushort idx in LDS half-buf

    #define STAGE_A(buf, u, h) do {                                          \
        const char* s_ = As + (size_t)(u) * 32768 + (h) * 16384 + soff;      \
        gload16(s_,        &Ab[buf][h][dsti]);                               \
        gload16(s_ + 1024, &Ab[buf][h][dsti + 512]);                         \
    } while (0)
    #define STAGE_B(buf, u, h) do {                                          \
        const char* s_ = Bs + (size_t)(u) * 32768 + (h) * 16384 + soff;      \
        gload16(s_,        &Bb[buf][h][dsti]);                               \
        gload16(s_ + 1024, &Bb[buf][h][dsti + 512]);                         \
    } while (0)

    bf16x8 a[4][2], b0[2][2], b1[2][2];

    #define LDA(sub) do {                                                    \
        _Pragma("unroll") for (int i = 0; i < 4; ++i)                        \
        _Pragma("unroll") for (int ks = 0; ks < 2; ++ks) {                   \
            const int rl = (sub) * 64 + i * 16 + (lane & 15);                \
            const int by = (rl * 128 + ks * 64 + ((lane >> 4) * 16))         \
                           ^ ((rl & 7) << 4);                                \
            a[i][ks] = __builtin_bit_cast(bf16x8,                            \
                *reinterpret_cast<const us8*>(                               \
                    (const char*)&Ab[cur][wm][0] + by));                     \
        } } while (0)
    #define LDB(breg, q) do {                                                \
        _Pragma("unroll") for (int j = 0; j < 2; ++j)                        \
        _Pragma("unroll") for (int ks = 0; ks < 2; ++ks) {                   \
            const int cl = (wn & 1) * 64 + (q) * 32 + j * 16 + (lane & 15);  \
            const int by = (cl * 128 + ks * 64 + ((lane >> 4) * 16))         \
                           ^ ((cl & 7) << 4);                                \
            breg[j][ks] = __builtin_bit_cast(bf16x8,                         \
                *reinterpret_cast<const us8*>(                               \
                    (const char*)&Bb[cur][hB][0] + by));                     \
        } } while (0)
    #define MMA16(ib, jb, breg) do {                                         \
        _Pragma("unroll") for (int i = 0; i < 4; ++i)                        \
        _Pragma("unroll") for (int j = 0; j < 2; ++j)                        \
        _Pragma("unroll") for (int ks = 0; ks < 2; ++ks)                     \
            acc[(ib) + i][(jb) + j] = __builtin_amdgcn_mfma_f32_16x16x32_bf16( \
                a[i][ks], breg[j][ks], acc[(ib) + i][(jb) + j], 0, 0, 0);    \
    } while (0)

    // prologue: stage tiles 0 and 1 (16 loads); retire tile 0, keep tile 1
    STAGE_B(0, 0, 0); STAGE_B(0, 0, 1);
    STAGE_A(0, 0, 0); STAGE_A(0, 0, 1);
    STAGE_B(1, 1, 0); STAGE_B(1, 1, 1);
    STAGE_A(1, 1, 0); STAGE_A(1, 1, 1);
    asm volatile("s_waitcnt vmcnt(8)" ::: "memory");
    __builtin_amdgcn_sched_barrier(0);
    __builtin_amdgcn_s_barrier();

    int cur = 0;
    for (int u = 0; u < NT_K; ++u) {
        // ---- P1: ld B-q0 then A-sub0 (first-consumed first)
        LDB(b0, 0);
        LDA(0);
        __builtin_amdgcn_s_barrier();
        __builtin_amdgcn_s_setprio(1);
        MMA16(0, 0, b0);
        __builtin_amdgcn_s_setprio(0);
        __builtin_amdgcn_s_barrier();

        // ---- P2: ld B-q1
        LDB(b1, 1);
        __builtin_amdgcn_s_barrier();
        __builtin_amdgcn_s_setprio(1);
        MMA16(0, 2, b1);
        __builtin_amdgcn_s_setprio(0);
        __builtin_amdgcn_s_barrier();

        // ---- P3: stage both B halves (u+2) into [cur] || ld A-sub1
        __builtin_amdgcn_sched_barrier(0);
        if (u + 2 < NT_K) { STAGE_B(cur, u + 2, 0); STAGE_B(cur, u + 2, 1); }
        LDA(1);
        __builtin_amdgcn_s_barrier();
        __builtin_amdgcn_s_setprio(1);
        MMA16(4, 2, b1);
        __builtin_amdgcn_s_setprio(0);
        __builtin_amdgcn_s_barrier();

        // ---- P4: drain lgkm; stage A halves (u+2); counted vmcnt
        asm volatile("s_waitcnt lgkmcnt(0)" ::: "memory");
        __builtin_amdgcn_sched_barrier(0);
        if (u + 2 < NT_K) {
            STAGE_A(cur, u + 2, 0);
            STAGE_A(cur, u + 2, 1);
            asm volatile("s_waitcnt vmcnt(8)" ::: "memory");
        } else {
            asm volatile("s_waitcnt vmcnt(0)" ::: "memory");
        }
        __builtin_amdgcn_sched_barrier(0);
        __builtin_amdgcn_s_barrier();
        __builtin_amdgcn_s_setprio(1);
        MMA16(4, 0, b0);
        __builtin_amdgcn_s_setprio(0);
        __builtin_amdgcn_s_barrier();

        cur ^= 1;
    }
    #undef STAGE_A
    #undef STAGE_B
    #undef LDA
    #undef LDB
    #undef MMA16

    const int m0 = mt * 256, n0 = nt * 256;
    float bvj[4];
    #pragma unroll
    for (int j = 0; j < 4; ++j)
        bvj[j] = bias[n0 + wn * 64 + j * 16 + (lane & 15)];

    // pure store loop (no branches/atomics)
    #pragma unroll
    for (int j = 0; j < 4; ++j) {
        const int col = n0 + wn * 64 + j * 16 + (lane & 15);
        #pragma unroll
        for (int i = 0; i < 8; ++i) {
            const int rowb = m0 + wm * 128 + i * 16 + ((lane >> 4) * 4);
            #pragma unroll
            for (int r = 0; r < 4; ++r)
                C[(size_t)(rowb + r) * DICT + col] = acc[i][j][r] + bvj[j];
        }
    }

    // collection: thread-local 4-slot compare pass, then short emission.
    int nh = 0, h0 = 0, h1 = 0, h2 = 0, h3 = 0;
    #pragma unroll
    for (int j = 0; j < 4; ++j) {
        const int col = n0 + wn * 64 + j * 16 + (lane & 15);
        #pragma unroll
        for (int i = 0; i < 8; ++i) {
            const int rowb = m0 + wm * 128 + i * 16 + ((lane >> 4) * 4);
            #pragma unroll
            for (int r = 0; r < 4; ++r) {
                if (acc[i][j][r] + bvj[j] >= T_OPT) {
                    const int enc = ((rowb + r) << 15) | col;
                    if      (nh == 0) h0 = enc;
                    else if (nh == 1) h1 = enc;
                    else if (nh == 2) h2 = enc;
                    else if (nh == 3) h3 = enc;
                    else {
                        const int row2 = enc >> 15;
                        const int pos2 = atomicAdd(&cand_cnt[row2], 1);
                        if (pos2 < cap)
                            cand_idx[(size_t)row2 * cap + pos2] = enc & 0x7FFF;
                    }
                    ++nh;
                }
            }
        }
    }
    #pragma unroll
    for (int s2 = 0; s2 < 4; ++s2) {
        if (nh > s2) {
            const int enc = (s2 == 0) ? h0 : (s2 == 1) ? h1
                          : (s2 == 2) ? h2 : h3;
            const int row2 = enc >> 15;
            const int pos  = atomicAdd(&cand_cnt[row2], 1);
            if (pos < cap)
                cand_idx[(size_t)row2 * cap + pos] = enc & 0x7FFF;
        }
    }
}

// ---------------------------------------------------------------------------
// Exact f32 recompute + features-row zeroing + exact top-32 + scatter.
// ---------------------------------------------------------------------------
__global__ __launch_bounds__(256) void recompute_select_kernel(
    const float* __restrict__ x,
    const float* __restrict__ We,
    const float* __restrict__ be,
    const float* __restrict__ pre,
    const int*   __restrict__ cand_idx,
    const int*   __restrict__ cand_cnt,
    int cap,
    float* __restrict__ features,
    float* __restrict__ valsT,           // [KTOP][NROWS]
    int*   __restrict__ idxT)            // [KTOP][NROWS]
{
    __shared__ float xr[D_MODEL];
    __shared__ float cv[CAPMAX];
    __shared__ int   ci[CAPMAX];
    __shared__ float av_s[CAPMAX];
    __shared__ unsigned cnt_part[4];
    __shared__ unsigned hist[2048];
    __shared__ unsigned part[2][256];
    __shared__ int s_thr;
    __shared__ unsigned s_cnt;

    const int n    = blockIdx.x;
    const int t    = threadIdx.x;
    const int lane = t & 63;
    const int w    = t >> 6;
    const int rawcnt = cand_cnt[n];
    int cnt = rawcnt < cap ? rawcnt : cap;

    float4* frow = reinterpret_cast<float4*>(features + (size_t)n * DICT);
    const float4 z4 = make_float4(0.f, 0.f, 0.f, 0.f);
    #pragma unroll 8
    for (int i = t; i < DICT / 4; i += 256) frow[i] = z4;

    for (int i = t; i < D_MODEL / 4; i += 256)
        reinterpret_cast<float4*>(xr)[i] =
            reinterpret_cast<const float4*>(x + (size_t)n * D_MODEL)[i];
    for (int c = t; c < cnt; c += 256) ci[c] = cand_idx[(size_t)n * cap + c];
    __syncthreads();

    float av = -INFINITY;
    if (t < cnt) av = pre[(size_t)n * DICT + ci[t]];
    if (t < CAPMAX) av_s[t] = av;
    __syncthreads();

    float lo = 0.f, hi = 16.f;
    for (int it = 0; it < 18; ++it) {
        const float mid = 0.5f * (lo + hi);
        unsigned long long b = __ballot(av >= mid);
        if (lane == 0) cnt_part[w] = (unsigned)__popcll(b);
        __syncthreads();
        const int c32 = (int)(cnt_part[0] + cnt_part[1] + cnt_part[2] + cnt_part[3]);
        if (c32 >= KTOP) lo = mid; else hi = mid;
        __syncthreads();
    }
    float cutoff  = lo - 0.08f;
    float sure_hi = lo + 0.17f;

    const bool ok = (rawcnt <= cap) && (cnt >= KTOP) && (cutoff >= T_OPT);
    if (!ok) {
        for (int i = t; i < 2048; i += 256) hist[i] = 0;
        if (t == 0) { s_thr = -1; s_cnt = 0; }
        __syncthreads();
        const float4* srcp = reinterpret_cast<const float4*>(pre + (size_t)n * DICT);
        for (int p = 0; p < DICT / 1024; ++p) {
            float4 v = srcp[t + 256 * p];
            float e[4] = {v.x, v.y, v.z, v.w};
            #pragma unroll
            for (int j = 0; j < 4; ++j)
                if (e[j] > 0.f)
                    atomicAdd(&hist[__builtin_bit_cast(unsigned, e[j]) >> 20], 1u);
        }
        __syncthreads();
        unsigned hv[8];
        unsigned local = 0;
        #pragma unroll
        for (int b = 0; b < 8; ++b) { hv[b] = hist[t * 8 + b]; local += hv[b]; }
        part[0][t] = local;
        __syncthreads();
        int sb = 0;
        for (int s = 1; s < 256; s <<= 1) {
            unsigned v2 = part[sb][t];
            if (t + s < 256) v2 += part[sb][t + s];
            part[sb ^ 1][t] = v2;
            sb ^= 1;
            __syncthreads();
        }
        const unsigned above = (t < 255) ? part[sb][t + 1] : 0;
        unsigned cum = above;
        int mybin = -1;
        #pragma unroll
        for (int b = 7; b >= 0; --b) {
            cum += hv[b];
            if (mybin < 0 && cum >= NCAND_FB) mybin = t * 8 + b;
        }
        if (mybin >= 0) atomicMax(&s_thr, mybin);
        __syncthreads();
        const unsigned thrb = (s_thr < 0) ? 0u : (unsigned)s_thr;
        for (int p = 0; p < DICT / 1024; ++p) {
            float4 v = srcp[t + 256 * p];
            float e[4] = {v.x, v.y, v.z, v.w};
            #pragma unroll
            for (int j = 0; j < 4; ++j) {
                if (e[j] > 0.f &&
                    (__builtin_bit_cast(unsigned, e[j]) >> 20) >= thrb) {
                    unsigned pos = atomicAdd(&s_cnt, 1u);
                    if (pos < (unsigned)cap) {
                        ci[pos]   = (t + 256 * p) * 4 + j;
                        av_s[pos] = e[j];
                    }
                }
            }
        }
        __syncthreads();
        cnt = (int)min(s_cnt, (unsigned)cap);
        av = (t < cnt) ? av_s[t] : -INFINITY;
        lo = 0.f; hi = 16.f;
        for (int it = 0; it < 18; ++it) {
            const float mid = 0.5f * (lo + hi);
            unsigned long long b = __ballot(av >= mid);
            if (lane == 0) cnt_part[w] = (unsigned)__popcll(b);
            __syncthreads();
            const int c32 = (int)(cnt_part[0] + cnt_part[1] + cnt_part[2] + cnt_part[3]);
            if (c32 >= KTOP) lo = mid; else hi = mid;
            __syncthreads();
        }
        cutoff  = lo - 0.08f;
        sure_hi = lo + 0.17f;
    }

    for (int c = w; c < cnt; c += 4) {
        const float a_v = av_s[c];
        if (a_v < cutoff)   { if (lane == 0) cv[c] = -INFINITY; continue; }
        if (a_v > sure_hi)  { if (lane == 0) cv[c] = a_v;       continue; }
        const int idx = ci[c];
        const float4* wrow = reinterpret_cast<const float4*>(We + (size_t)idx * D_MODEL);
        const float4* xro  = reinterpret_cast<const float4*>(xr);
        float s = 0.f;
        #pragma unroll
        for (int p = 0; p < 8; ++p) {
            float4 a = xro[lane + 64 * p];
            float4 b = wrow[lane + 64 * p];
            s = fmaf(a.x, b.x, s); s = fmaf(a.y, b.y, s);
            s = fmaf(a.z, b.z, s); s = fmaf(a.w, b.w, s);
        }
        #pragma unroll
        for (int sh = 1; sh < 64; sh <<= 1) s += __shfl_xor(s, sh);
        if (lane == 0) cv[c] = s + be[idx];
    }
    __syncthreads();

    if (w == 0) {
        float pv[CAPMAX / 64];
        int   pi[CAPMAX / 64];
        #pragma unroll
        for (int qq = 0; qq < CAPMAX / 64; ++qq) {
            const int c = lane + 64 * qq;
            const bool okc = c < cnt;
            pv[qq] = okc ? cv[c] : -INFINITY;
            pi[qq] = okc ? ci[c] : 0x7fffffff;
        }
        for (int r = 0; r < KTOP; ++r) {
            float bv = pv[0]; int bi = pi[0]; int bq = 0;
            #pragma unroll
            for (int qq = 1; qq < CAPMAX / 64; ++qq)
                if (pv[qq] > bv || (pv[qq] == bv && pi[qq] < bi)) {
                    bv = pv[qq]; bi = pi[qq]; bq = qq;
                }
            float gv = bv; int gi = bi;
            #pragma unroll
            for (int s = 1; s < 64; s <<= 1) {
                float ov = __shfl_xor(gv, s);
                int   oi = __shfl_xor(gi, s);
                if (ov > gv || (ov == gv && oi < gi)) { gv = ov; gi = oi; }
            }
            if (bi == gi) pv[bq] = -INFINITY;
            if (lane == 0) {
                const bool valid = (gi != 0x7fffffff) && (gv != -INFINITY);
                const float rv = (valid && gv > 0.f) ? gv : 0.f;
                valsT[r * NROWS + n] = rv;
                idxT[r * NROWS + n]  = valid ? gi : 0;
                if (valid) features[(size_t)n * DICT + gi] = rv;
            }
        }
    }
}

// ---------------------------------------------------------------------------
// Decoder (r21): block per d, Wd row in LDS; writes TRANSPOSED reconT[d][n]
// (lane-consecutive n -> fully coalesced stores; the old recon[n][d] stores
// were 8KB-strided: 4B per cache line, ~130 MB HBM write for 16 MB useful).
// A separate in-place transpose restores row-major recon.
// ---------------------------------------------------------------------------
__global__ __launch_bounds__(1024) void decoder_kernel(
    const float* __restrict__ Wd,
    const float* __restrict__ bd,
    const float* __restrict__ valsT,     // [KTOP][NROWS]
    const int*   __restrict__ idxT,      // [KTOP][NROWS]
    float* __restrict__ reconT)          // [D_MODEL][NROWS]
{
    __shared__ float wrow[DICT];         // 128 KB
    const int d = blockIdx.x;
    const int t = threadIdx.x;
    const float* src = Wd + (size_t)d * DICT;

    for (int i = t; i < DICT / 4; i += 1024)
        reinterpret_cast<float4*>(wrow)[i] =
            reinterpret_cast<const float4*>(src)[i];
    __syncthreads();

    const float b = bd[d];
    #pragma unroll
    for (int u = 0; u < NROWS / 1024; ++u) {
        const int n = t + 1024 * u;
        float a0 = 0.f, a1 = 0.f, a2 = 0.f, a3 = 0.f;
        #pragma unroll
        for (int k = 0; k < KTOP; k += 8) {
            float v0 = valsT[(k + 0) * NROWS + n];
            float v1 = valsT[(k + 1) * NROWS + n];
            float v2 = valsT[(k + 2) * NROWS + n];
            float v3 = valsT[(k + 3) * NROWS + n];
            float v4 = valsT[(k + 4) * NROWS + n];
            float v5 = valsT[(k + 5) * NROWS + n];
            float v6 = valsT[(k + 6) * NROWS + n];
            float v7 = valsT[(k + 7) * NROWS + n];
            int i0 = idxT[(k + 0) * NROWS + n];
            int i1 = idxT[(k + 1) * NROWS + n];
            int i2 = idxT[(k + 2) * NROWS + n];
            int i3 = idxT[(k + 3) * NROWS + n];
            int i4 = idxT[(k + 4) * NROWS + n];
            int i5 = idxT[(k + 5) * NROWS + n];
            int i6 = idxT[(k + 6) * NROWS + n];
            int i7 = idxT[(k + 7) * NROWS + n];
            a0 = fmaf(v0, wrow[i0], a0);
            a1 = fmaf(v1, wrow[i1], a1);
            a2 = fmaf(v2, wrow[i2], a2);
            a3 = fmaf(v3, wrow[i3], a3);
            a0 = fmaf(v4, wrow[i4], a0);
            a1 = fmaf(v5, wrow[i5], a1);
            a2 = fmaf(v6, wrow[i6], a2);
            a3 = fmaf(v7, wrow[i7], a3);
        }
        reconT[(size_t)d * NROWS + n] = ((a0 + a1) + (a2 + a3)) + b;
    }
}

// ---------------------------------------------------------------------------
// In-place transpose of the 2048x2048 recon matrix (reconT -> recon).
// 64x64 LDS tiles (+1 pad), one block per (ti,tj) pair with ti<=tj.
// ---------------------------------------------------------------------------
#define TT 64
#define NTILE (NROWS / TT)   // 32
__global__ __launch_bounds__(256) void transpose_inplace(float* __restrict__ M)
{
    __shared__ float ta[TT][TT + 1];
    __shared__ float tb[TT][TT + 1];

    int rem = blockIdx.x;
    int ti = 0;
    while (rem >= NTILE - ti) { rem -= NTILE - ti; ++ti; }
    const int tj = ti + rem;

    const int t  = threadIdx.x;
    const int c  = t & 63;
    const int r0 = t >> 6;       // 0..3

    float* Aij = M + (size_t)(ti * TT) * NROWS + tj * TT;
    float* Aji = M + (size_t)(tj * TT) * NROWS + ti * TT;

    if (ti == tj) {
        #pragma unroll
        for (int r = r0; r < TT; r += 4)
            ta[r][c] = Aij[(size_t)r * NROWS + c];
        __syncthreads();
        #pragma unroll
        for (int r = r0; r < TT; r += 4)
            Aij[(size_t)r * NROWS + c] = ta[c][r];
    } else {
        #pragma unroll
        for (int r = r0; r < TT; r += 4) {
            ta[r][c] = Aij[(size_t)r * NROWS + c];
            tb[r][c] = Aji[(size_t)r * NROWS + c];
        }
        __syncthreads();
        #pragma unroll
        for (int r = r0; r < TT; r += 4) {
            Aij[(size_t)r * NROWS + c] = tb[c][r];
            Aji[(size_t)r * NROWS + c] = ta[c][r];
        }
    }
}

// ---------------------------------------------------------------------------
extern "C" void kernel_launch(void* const* d_in, const int* in_sizes, int n_in,
                              void* d_out, int out_size, void* d_ws, size_t ws_size,
                              hipStream_t stream)
{
    const float* x  = (const float*)d_in[0];
    const float* We = (const float*)d_in[1];
    const float* be = (const float*)d_in[2];
    const float* Wd = (const float*)d_in[3];
    const float* bd = (const float*)d_in[4];

    float* out      = (float*)d_out;
    float* recon    = out;
    float* features = out + (size_t)NROWS * D_MODEL;
    float* pre      = features + (size_t)NROWS * DICT;

    // bf16 tiled operands parked in the features region (overwritten by
    // recompute's per-row zeroing of features)
    unsigned short* webf = (unsigned short*)features;                 // 128 MB
    unsigned short* xbf  = webf + (size_t)TNB * NT_K * 16384;         // + 8 MB

    long cap_l = (long)(ws_size / 4 - (size_t)NROWS * (1 + 2 * KTOP)) / NROWS;
    int cap = (int)(cap_l < 64 ? 64 : (cap_l > CAPMAX ? CAPMAX : cap_l));

    char* ws = (char*)d_ws;
    int*   ws_cand  = (int*)ws;
    int*   ws_cnt   = (int*)(ws + (size_t)NROWS * cap * 4);
    float* ws_valsT = (float*)(ws + (size_t)NROWS * (cap + 1) * 4);
    int*   ws_idxT  = (int*)(ws + (size_t)NROWS * (cap + 1 + KTOP) * 4);

    // 0) zero per-row candidate counters
    hipMemsetAsync(ws_cnt, 0, (size_t)NROWS * sizeof(int), stream);

    // 1) convert + tile + swizzle operands to bf16
    const int conv_blocks = (int)(((size_t)NROWS * 64 + (size_t)DICT * 64) / 256);
    convert_tiles<<<conv_blocks, 256, 0, stream>>>(x, We, xbf, webf);

    // 2) encoder GEMM -> approx pre_acts + fused candidate collection
    encoder_bf16<<<TMB * TNB, 512, 0, stream>>>(
        xbf, webf, be, pre, ws_cand, ws_cnt, cap);

    // 3) banded exact recompute + features zeroing + top-32 + scatter
    recompute_select_kernel<<<NROWS, 256, 0, stream>>>(
        x, We, be, pre, ws_cand, ws_cnt, cap, features, ws_valsT, ws_idxT);

    // 4) sparse decoder (coalesced transposed writes into recon region)
    decoder_kernel<<<D_MODEL, 1024, 0, stream>>>(
        Wd, bd, ws_valsT, ws_idxT, recon);

    // 5) in-place transpose reconT -> recon
    transpose_inplace<<<NTILE * (NTILE + 1) / 2, 256, 0, stream>>>(recon);
}

// Round 22
// 705.203 us; speedup vs baseline: 1.1490x; 1.0123x over previous
//
#include <hip/hip_runtime.h>
#include <cstddef>
#include <cstdint>
#include <cmath>

#define D_MODEL 2048
#define DICT    32768
#define KTOP    32
#define NCAND_FB 96         // fallback hist margin (rank cum >= 96)
#define CAPMAX  256
#define T_OPT   2.70f       // epilogue collect threshold
#define BKT     64                  // K-tile depth
#define NT_K    (D_MODEL / BKT)     // 32 K-tiles
#define NROWS   2048
#define TMB     (NROWS / 256)       // 8  row tiles
#define TNB     (DICT / 256)        // 128 col tiles
#define SENT    1000.0f             // sure-in selection sentinel offset

typedef float    f32x4  __attribute__((ext_vector_type(4)));
typedef __bf16   bf16x8 __attribute__((ext_vector_type(8)));
typedef unsigned short us8 __attribute__((ext_vector_type(8)));

__device__ __forceinline__ unsigned short f2bf_rne(float f) {
    unsigned u = __builtin_bit_cast(unsigned, f);
    unsigned r = u + 0x7fffu + ((u >> 16) & 1u);
    return (unsigned short)(r >> 16);
}

__device__ __forceinline__ void gload16(const void* g, const void* s) {
    __builtin_amdgcn_global_load_lds(
        (const __attribute__((address_space(1))) unsigned int*)g,
        (__attribute__((address_space(3))) unsigned int*)s, 16, 0, 0);
}

// ---------------------------------------------------------------------------
// Convert x and We f32 -> bf16, pre-tiled per 256-row tile into 32 K-tiles of
// 64 k; inverse-swizzled source layout (byte ^= (rloc&7)<<4 per 128B line).
// ---------------------------------------------------------------------------
__global__ __launch_bounds__(256) void convert_tiles(
    const float* __restrict__ x,
    const float* __restrict__ We,
    unsigned short* __restrict__ xbf,     // [TMB][NT_K][16384] ushorts
    unsigned short* __restrict__ webf)    // [TNB][NT_K][16384] ushorts
{
    const size_t NX = (size_t)NROWS * 64;
    size_t id = (size_t)blockIdx.x * 256 + threadIdx.x;

    const float* src;
    unsigned short* dstb;
    int row, s;
    if (id < NX) {
        row = (int)(id >> 6); s = (int)(id & 63);
        src = x + (size_t)row * D_MODEL + s * 32;
        dstb = xbf + ((size_t)(row >> 8) * NT_K + (s >> 1)) * 16384
                   + ((row >> 7) & 1) * 8192;
    } else {
        id -= NX;
        row = (int)(id >> 6); s = (int)(id & 63);
        src = We + (size_t)row * D_MODEL + s * 32;
        dstb = webf + ((size_t)(row >> 8) * NT_K + (s >> 1)) * 16384
                    + ((row >> 7) & 1) * 8192;
    }
    const int rloc = row & 127;
    const int koff = (s & 1) * 64;

    #pragma unroll
    for (int qc = 0; qc < 4; ++qc) {
        float4 v0 = reinterpret_cast<const float4*>(src)[qc * 2];
        float4 v1 = reinterpret_cast<const float4*>(src)[qc * 2 + 1];
        us8 c;
        c[0] = f2bf_rne(v0.x); c[1] = f2bf_rne(v0.y);
        c[2] = f2bf_rne(v0.z); c[3] = f2bf_rne(v0.w);
        c[4] = f2bf_rne(v1.x); c[5] = f2bf_rne(v1.y);
        c[6] = f2bf_rne(v1.z); c[7] = f2bf_rne(v1.w);
        const int byteoff = (rloc * 128 + koff + qc * 16) ^ ((rloc & 7) << 4);
        *reinterpret_cast<us8*>(reinterpret_cast<char*>(dstb) + byteoff) = c;
    }
}

// ---------------------------------------------------------------------------
// Encoder GEMM — r20 config (best verified: ~355 us, MfmaUtil 33%, 0 bank
// conflicts): 256x256 tile, BK=64, deep vmcnt(8) pipeline, compiler-managed
// lgkm waits, fused candidate collection (4-slot + atomics).
// ---------------------------------------------------------------------------
__global__ __launch_bounds__(512, 2) void encoder_bf16(
    const unsigned short* __restrict__ xbf,
    const unsigned short* __restrict__ webf,
    const float* __restrict__ bias,
    float* __restrict__ C,
    int* __restrict__ cand_idx,           // [NROWS][cap]
    int* __restrict__ cand_cnt,           // [NROWS], pre-zeroed
    int cap)
{
    __shared__ __align__(16) unsigned short Ab[2][2][8192];   // [dbuf][half]
    __shared__ __align__(16) unsigned short Bb[2][2][8192];

    const int t    = threadIdx.x;
    const int lane = t & 63;
    const int w    = t >> 6;        // 0..7
    const int wm   = w >> 2;        // 0..1  (128-row half; = A half index)
    const int wn   = w & 3;         // 0..3  (64-col slice)
    const int hB   = wn >> 1;       // B half index

    const int bid = blockIdx.x;
    const int swz = (bid & 7) * (TMB * TNB / 8) + (bid >> 3);
    const int mt  = swz & (TMB - 1);
    const int nt  = swz >> 3;

    const char* As = (const char*)xbf  + (size_t)mt * (NT_K * 32768);
    const char* Bs = (const char*)webf + (size_t)nt * (NT_K * 32768);

    f32x4 acc[8][4];
    #pragma unroll
    for (int i = 0; i < 8; ++i)
        #pragma unroll
        for (int j = 0; j < 4; ++j) acc[i][j] = (f32x4)0.f;

    const int soff = w * 2048 + lane * 16;   // byte offset in half-tile block
    const int dsti = w * 1024 + lane * 8;    // ushort idx in LDS half-buf

    #define STAGE_A(buf, u, h) do {                                          \
        const char* s_ = As + (size_t)(u) * 32768 + (h) * 16384 + soff;      \
        gload16(s_,        &Ab[buf][h][dsti]);                               \
        gload16(s_ + 1024, &Ab[buf][h][dsti + 512]);                         \
    } while (0)
    #define STAGE_B(buf, u, h) do {                                          \
        const char* s_ = Bs + (size_t)(u) * 32768 + (h) * 16384 + soff;      \
        gload16(s_,        &Bb[buf][h][dsti]);                               \
        gload16(s_ + 1024, &Bb[buf][h][dsti + 512]);                         \
    } while (0)

    bf16x8 a[4][2], b0[2][2], b1[2][2];

    #define LDA(sub) do {                                                    \
        _Pragma("unroll") for (int i = 0; i < 4; ++i)                        \
        _Pragma("unroll") for (int ks = 0; ks < 2; ++ks) {                   \
            const int rl = (sub) * 64 + i * 16 + (lane & 15);                \
            const int by = (rl * 128 + ks * 64 + ((lane >> 4) * 16))         \
                           ^ ((rl & 7) << 4);                                \
            a[i][ks] = __builtin_bit_cast(bf16x8,                            \
                *reinterpret_cast<const us8*>(                               \
                    (const char*)&Ab[cur][wm][0] + by));                     \
        } } while (0)
    #define LDB(breg, q) do {                                                \
        _Pragma("unroll") for (int j = 0; j < 2; ++j)                        \
        _Pragma("unroll") for (int ks = 0; ks < 2; ++ks) {                   \
            const int cl = (wn & 1) * 64 + (q) * 32 + j * 16 + (lane & 15);  \
            const int by = (cl * 128 + ks * 64 + ((lane >> 4) * 16))         \
                           ^ ((cl & 7) << 4);                                \
            breg[j][ks] = __builtin_bit_cast(bf16x8,                         \
                *reinterpret_cast<const us8*>(                               \
                    (const char*)&Bb[cur][hB][0] + by));                     \
        } } while (0)
    #define MMA16(ib, jb, breg) do {                                         \
        _Pragma("unroll") for (int i = 0; i < 4; ++i)                        \
        _Pragma("unroll") for (int j = 0; j < 2; ++j)                        \
        _Pragma("unroll") for (int ks = 0; ks < 2; ++ks)                     \
            acc[(ib) + i][(jb) + j] = __builtin_amdgcn_mfma_f32_16x16x32_bf16( \
                a[i][ks], breg[j][ks], acc[(ib) + i][(jb) + j], 0, 0, 0);    \
    } while (0)

    // prologue: stage tiles 0 and 1 (16 loads); retire tile 0, keep tile 1
    STAGE_B(0, 0, 0); STAGE_B(0, 0, 1);
    STAGE_A(0, 0, 0); STAGE_A(0, 0, 1);
    STAGE_B(1, 1, 0); STAGE_B(1, 1, 1);
    STAGE_A(1, 1, 0); STAGE_A(1, 1, 1);
    asm volatile("s_waitcnt vmcnt(8)" ::: "memory");
    __builtin_amdgcn_sched_barrier(0);
    __builtin_amdgcn_s_barrier();

    int cur = 0;
    for (int u = 0; u < NT_K; ++u) {
        // ---- P1: ld B-q0 then A-sub0 (first-consumed first)
        LDB(b0, 0);
        LDA(0);
        __builtin_amdgcn_s_barrier();
        __builtin_amdgcn_s_setprio(1);
        MMA16(0, 0, b0);
        __builtin_amdgcn_s_setprio(0);
        __builtin_amdgcn_s_barrier();

        // ---- P2: ld B-q1
        LDB(b1, 1);
        __builtin_amdgcn_s_barrier();
        __builtin_amdgcn_s_setprio(1);
        MMA16(0, 2, b1);
        __builtin_amdgcn_s_setprio(0);
        __builtin_amdgcn_s_barrier();

        // ---- P3: stage both B halves (u+2) into [cur] || ld A-sub1
        __builtin_amdgcn_sched_barrier(0);
        if (u + 2 < NT_K) { STAGE_B(cur, u + 2, 0); STAGE_B(cur, u + 2, 1); }
        LDA(1);
        __builtin_amdgcn_s_barrier();
        __builtin_amdgcn_s_setprio(1);
        MMA16(4, 2, b1);
        __builtin_amdgcn_s_setprio(0);
        __builtin_amdgcn_s_barrier();

        // ---- P4: drain lgkm; stage A halves (u+2); counted vmcnt
        asm volatile("s_waitcnt lgkmcnt(0)" ::: "memory");
        __builtin_amdgcn_sched_barrier(0);
        if (u + 2 < NT_K) {
            STAGE_A(cur, u + 2, 0);
            STAGE_A(cur, u + 2, 1);
            asm volatile("s_waitcnt vmcnt(8)" ::: "memory");
        } else {
            asm volatile("s_waitcnt vmcnt(0)" ::: "memory");
        }
        __builtin_amdgcn_sched_barrier(0);
        __builtin_amdgcn_s_barrier();
        __builtin_amdgcn_s_setprio(1);
        MMA16(4, 0, b0);
        __builtin_amdgcn_s_setprio(0);
        __builtin_amdgcn_s_barrier();

        cur ^= 1;
    }
    #undef STAGE_A
    #undef STAGE_B
    #undef LDA
    #undef LDB
    #undef MMA16

    const int m0 = mt * 256, n0 = nt * 256;
    float bvj[4];
    #pragma unroll
    for (int j = 0; j < 4; ++j)
        bvj[j] = bias[n0 + wn * 64 + j * 16 + (lane & 15)];

    // pure store loop (no branches/atomics)
    #pragma unroll
    for (int j = 0; j < 4; ++j) {
        const int col = n0 + wn * 64 + j * 16 + (lane & 15);
        #pragma unroll
        for (int i = 0; i < 8; ++i) {
            const int rowb = m0 + wm * 128 + i * 16 + ((lane >> 4) * 4);
            #pragma unroll
            for (int r = 0; r < 4; ++r)
                C[(size_t)(rowb + r) * DICT + col] = acc[i][j][r] + bvj[j];
        }
    }

    // collection: thread-local 4-slot compare pass, then short emission.
    int nh = 0, h0 = 0, h1 = 0, h2 = 0, h3 = 0;
    #pragma unroll
    for (int j = 0; j < 4; ++j) {
        const int col = n0 + wn * 64 + j * 16 + (lane & 15);
        #pragma unroll
        for (int i = 0; i < 8; ++i) {
            const int rowb = m0 + wm * 128 + i * 16 + ((lane >> 4) * 4);
            #pragma unroll
            for (int r = 0; r < 4; ++r) {
                if (acc[i][j][r] + bvj[j] >= T_OPT) {
                    const int enc = ((rowb + r) << 15) | col;
                    if      (nh == 0) h0 = enc;
                    else if (nh == 1) h1 = enc;
                    else if (nh == 2) h2 = enc;
                    else if (nh == 3) h3 = enc;
                    else {
                        const int row2 = enc >> 15;
                        const int pos2 = atomicAdd(&cand_cnt[row2], 1);
                        if (pos2 < cap)
                            cand_idx[(size_t)row2 * cap + pos2] = enc & 0x7FFF;
                    }
                    ++nh;
                }
            }
        }
    }
    #pragma unroll
    for (int s2 = 0; s2 < 4; ++s2) {
        if (nh > s2) {
            const int enc = (s2 == 0) ? h0 : (s2 == 1) ? h1
                          : (s2 == 2) ? h2 : h3;
            const int row2 = enc >> 15;
            const int pos  = atomicAdd(&cand_cnt[row2], 1);
            if (pos < cap)
                cand_idx[(size_t)row2 * cap + pos] = enc & 0x7FFF;
        }
    }
}

// ---------------------------------------------------------------------------
// Exact f32 recompute + features-row zeroing + exact top-32 + scatter.
// r22 bands (set-proof hardened): skip (approx < m32-0.08, provably out);
// sure-in (approx > m32+0.085, provably in: any truly-greater d has
// approx_d > approx_c-0.08 > m32, and only 31 approx values exceed m32) —
// selection key gets +SENT so NO ambiguous candidate can displace a sure-in
// (fixes the latent mixed-ranking hole; output ORDER is irrelevant — only
// the set and values feed recon/features); ambiguous: exact f32 dot.
// ---------------------------------------------------------------------------
__global__ __launch_bounds__(256) void recompute_select_kernel(
    const float* __restrict__ x,
    const float* __restrict__ We,
    const float* __restrict__ be,
    const float* __restrict__ pre,
    const int*   __restrict__ cand_idx,
    const int*   __restrict__ cand_cnt,
    int cap,
    float* __restrict__ features,
    float* __restrict__ valsT,           // [KTOP][NROWS]
    int*   __restrict__ idxT)            // [KTOP][NROWS]
{
    __shared__ float xr[D_MODEL];
    __shared__ float cv[CAPMAX];
    __shared__ int   ci[CAPMAX];
    __shared__ float av_s[CAPMAX];
    __shared__ unsigned cnt_part[4];
    __shared__ unsigned hist[2048];
    __shared__ unsigned part[2][256];
    __shared__ int s_thr;
    __shared__ unsigned s_cnt;

    const int n    = blockIdx.x;
    const int t    = threadIdx.x;
    const int lane = t & 63;
    const int w    = t >> 6;
    const int rawcnt = cand_cnt[n];
    int cnt = rawcnt < cap ? rawcnt : cap;

    float4* frow = reinterpret_cast<float4*>(features + (size_t)n * DICT);
    const float4 z4 = make_float4(0.f, 0.f, 0.f, 0.f);
    #pragma unroll 8
    for (int i = t; i < DICT / 4; i += 256) frow[i] = z4;

    for (int i = t; i < D_MODEL / 4; i += 256)
        reinterpret_cast<float4*>(xr)[i] =
            reinterpret_cast<const float4*>(x + (size_t)n * D_MODEL)[i];
    for (int c = t; c < cnt; c += 256) ci[c] = cand_idx[(size_t)n * cap + c];
    __syncthreads();

    float av = -INFINITY;
    if (t < cnt) av = pre[(size_t)n * DICT + ci[t]];
    if (t < CAPMAX) av_s[t] = av;
    __syncthreads();

    float lo = 0.f, hi = 16.f;
    for (int it = 0; it < 18; ++it) {
        const float mid = 0.5f * (lo + hi);
        unsigned long long b = __ballot(av >= mid);
        if (lane == 0) cnt_part[w] = (unsigned)__popcll(b);
        __syncthreads();
        const int c32 = (int)(cnt_part[0] + cnt_part[1] + cnt_part[2] + cnt_part[3]);
        if (c32 >= KTOP) lo = mid; else hi = mid;
        __syncthreads();
    }
    float cutoff  = lo - 0.08f;
    float sure_hi = lo + 0.085f;

    const bool ok = (rawcnt <= cap) && (cnt >= KTOP) && (cutoff >= T_OPT);
    if (!ok) {
        for (int i = t; i < 2048; i += 256) hist[i] = 0;
        if (t == 0) { s_thr = -1; s_cnt = 0; }
        __syncthreads();
        const float4* srcp = reinterpret_cast<const float4*>(pre + (size_t)n * DICT);
        for (int p = 0; p < DICT / 1024; ++p) {
            float4 v = srcp[t + 256 * p];
            float e[4] = {v.x, v.y, v.z, v.w};
            #pragma unroll
            for (int j = 0; j < 4; ++j)
                if (e[j] > 0.f)
                    atomicAdd(&hist[__builtin_bit_cast(unsigned, e[j]) >> 20], 1u);
        }
        __syncthreads();
        unsigned hv[8];
        unsigned local = 0;
        #pragma unroll
        for (int b = 0; b < 8; ++b) { hv[b] = hist[t * 8 + b]; local += hv[b]; }
        part[0][t] = local;
        __syncthreads();
        int sb = 0;
        for (int s = 1; s < 256; s <<= 1) {
            unsigned v2 = part[sb][t];
            if (t + s < 256) v2 += part[sb][t + s];
            part[sb ^ 1][t] = v2;
            sb ^= 1;
            __syncthreads();
        }
        const unsigned above = (t < 255) ? part[sb][t + 1] : 0;
        unsigned cum = above;
        int mybin = -1;
        #pragma unroll
        for (int b = 7; b >= 0; --b) {
            cum += hv[b];
            if (mybin < 0 && cum >= NCAND_FB) mybin = t * 8 + b;
        }
        if (mybin >= 0) atomicMax(&s_thr, mybin);
        __syncthreads();
        const unsigned thrb = (s_thr < 0) ? 0u : (unsigned)s_thr;
        for (int p = 0; p < DICT / 1024; ++p) {
            float4 v = srcp[t + 256 * p];
            float e[4] = {v.x, v.y, v.z, v.w};
            #pragma unroll
            for (int j = 0; j < 4; ++j) {
                if (e[j] > 0.f &&
                    (__builtin_bit_cast(unsigned, e[j]) >> 20) >= thrb) {
                    unsigned pos = atomicAdd(&s_cnt, 1u);
                    if (pos < (unsigned)cap) {
                        ci[pos]   = (t + 256 * p) * 4 + j;
                        av_s[pos] = e[j];
                    }
                }
            }
        }
        __syncthreads();
        cnt = (int)min(s_cnt, (unsigned)cap);
        av = (t < cnt) ? av_s[t] : -INFINITY;
        lo = 0.f; hi = 16.f;
        for (int it = 0; it < 18; ++it) {
            const float mid = 0.5f * (lo + hi);
            unsigned long long b = __ballot(av >= mid);
            if (lane == 0) cnt_part[w] = (unsigned)__popcll(b);
            __syncthreads();
            const int c32 = (int)(cnt_part[0] + cnt_part[1] + cnt_part[2] + cnt_part[3]);
            if (c32 >= KTOP) lo = mid; else hi = mid;
            __syncthreads();
        }
        cutoff  = lo - 0.08f;
        sure_hi = lo + 0.085f;
    }

    for (int c = w; c < cnt; c += 4) {
        const float a_v = av_s[c];
        if (a_v < cutoff)   { if (lane == 0) cv[c] = -INFINITY;    continue; }
        if (a_v > sure_hi)  { if (lane == 0) cv[c] = a_v + SENT;   continue; }
        const int idx = ci[c];
        const float4* wrow = reinterpret_cast<const float4*>(We + (size_t)idx * D_MODEL);
        const float4* xro  = reinterpret_cast<const float4*>(xr);
        float s = 0.f;
        #pragma unroll
        for (int p = 0; p < 8; ++p) {
            float4 a = xro[lane + 64 * p];
            float4 b = wrow[lane + 64 * p];
            s = fmaf(a.x, b.x, s); s = fmaf(a.y, b.y, s);
            s = fmaf(a.z, b.z, s); s = fmaf(a.w, b.w, s);
        }
        #pragma unroll
        for (int sh = 1; sh < 64; sh <<= 1) s += __shfl_xor(s, sh);
        if (lane == 0) cv[c] = s + be[idx];
    }
    __syncthreads();

    if (w == 0) {
        float pv[CAPMAX / 64];
        int   pi[CAPMAX / 64];
        #pragma unroll
        for (int qq = 0; qq < CAPMAX / 64; ++qq) {
            const int c = lane + 64 * qq;
            const bool okc = c < cnt;
            pv[qq] = okc ? cv[c] : -INFINITY;
            pi[qq] = okc ? ci[c] : 0x7fffffff;
        }
        for (int r = 0; r < KTOP; ++r) {
            float bv = pv[0]; int bi = pi[0]; int bq = 0;
            #pragma unroll
            for (int qq = 1; qq < CAPMAX / 64; ++qq)
                if (pv[qq] > bv || (pv[qq] == bv && pi[qq] < bi)) {
                    bv = pv[qq]; bi = pi[qq]; bq = qq;
                }
            float gv = bv; int gi = bi;
            #pragma unroll
            for (int s = 1; s < 64; s <<= 1) {
                float ov = __shfl_xor(gv, s);
                int   oi = __shfl_xor(gi, s);
                if (ov > gv || (ov == gv && oi < gi)) { gv = ov; gi = oi; }
            }
            if (bi == gi) pv[bq] = -INFINITY;
            if (lane == 0) {
                const bool valid = (gi != 0x7fffffff) && (gv != -INFINITY);
                float base = gv;
                if (base > 500.f) base -= SENT;   // strip sure-in sentinel
                const float rv = (valid && base > 0.f) ? base : 0.f;
                valsT[r * NROWS + n] = rv;
                idxT[r * NROWS + n]  = valid ? gi : 0;
                if (valid) features[(size_t)n * DICT + gi] = rv;
            }
        }
    }
}

// ---------------------------------------------------------------------------
// Decoder: block per d, Wd row in LDS; writes TRANSPOSED reconT[d][n]
// (coalesced); separate in-place transpose restores row-major recon.
// ---------------------------------------------------------------------------
__global__ __launch_bounds__(1024) void decoder_kernel(
    const float* __restrict__ Wd,
    const float* __restrict__ bd,
    const float* __restrict__ valsT,     // [KTOP][NROWS]
    const int*   __restrict__ idxT,      // [KTOP][NROWS]
    float* __restrict__ reconT)          // [D_MODEL][NROWS]
{
    __shared__ float wrow[DICT];         // 128 KB
    const int d = blockIdx.x;
    const int t = threadIdx.x;
    const float* src = Wd + (size_t)d * DICT;

    for (int i = t; i < DICT / 4; i += 1024)
        reinterpret_cast<float4*>(wrow)[i] =
            reinterpret_cast<const float4*>(src)[i];
    __syncthreads();

    const float b = bd[d];
    #pragma unroll
    for (int u = 0; u < NROWS / 1024; ++u) {
        const int n = t + 1024 * u;
        float a0 = 0.f, a1 = 0.f, a2 = 0.f, a3 = 0.f;
        #pragma unroll
        for (int k = 0; k < KTOP; k += 8) {
            float v0 = valsT[(k + 0) * NROWS + n];
            float v1 = valsT[(k + 1) * NROWS + n];
            float v2 = valsT[(k + 2) * NROWS + n];
            float v3 = valsT[(k + 3) * NROWS + n];
            float v4 = valsT[(k + 4) * NROWS + n];
            float v5 = valsT[(k + 5) * NROWS + n];
            float v6 = valsT[(k + 6) * NROWS + n];
            float v7 = valsT[(k + 7) * NROWS + n];
            int i0 = idxT[(k + 0) * NROWS + n];
            int i1 = idxT[(k + 1) * NROWS + n];
            int i2 = idxT[(k + 2) * NROWS + n];
            int i3 = idxT[(k + 3) * NROWS + n];
            int i4 = idxT[(k + 4) * NROWS + n];
            int i5 = idxT[(k + 5) * NROWS + n];
            int i6 = idxT[(k + 6) * NROWS + n];
            int i7 = idxT[(k + 7) * NROWS + n];
            a0 = fmaf(v0, wrow[i0], a0);
            a1 = fmaf(v1, wrow[i1], a1);
            a2 = fmaf(v2, wrow[i2], a2);
            a3 = fmaf(v3, wrow[i3], a3);
            a0 = fmaf(v4, wrow[i4], a0);
            a1 = fmaf(v5, wrow[i5], a1);
            a2 = fmaf(v6, wrow[i6], a2);
            a3 = fmaf(v7, wrow[i7], a3);
        }
        reconT[(size_t)d * NROWS + n] = ((a0 + a1) + (a2 + a3)) + b;
    }
}

// ---------------------------------------------------------------------------
// In-place transpose of the 2048x2048 recon matrix (reconT -> recon).
// ---------------------------------------------------------------------------
#define TT 64
#define NTILE (NROWS / TT)   // 32
__global__ __launch_bounds__(256) void transpose_inplace(float* __restrict__ M)
{
    __shared__ float ta[TT][TT + 1];
    __shared__ float tb[TT][TT + 1];

    int rem = blockIdx.x;
    int ti = 0;
    while (rem >= NTILE - ti) { rem -= NTILE - ti; ++ti; }
    const int tj = ti + rem;

    const int t  = threadIdx.x;
    const int c  = t & 63;
    const int r0 = t >> 6;       // 0..3

    float* Aij = M + (size_t)(ti * TT) * NROWS + tj * TT;
    float* Aji = M + (size_t)(tj * TT) * NROWS + ti * TT;

    if (ti == tj) {
        #pragma unroll
        for (int r = r0; r < TT; r += 4)
            ta[r][c] = Aij[(size_t)r * NROWS + c];
        __syncthreads();
        #pragma unroll
        for (int r = r0; r < TT; r += 4)
            Aij[(size_t)r * NROWS + c] = ta[c][r];
    } else {
        #pragma unroll
        for (int r = r0; r < TT; r += 4) {
            ta[r][c] = Aij[(size_t)r * NROWS + c];
            tb[r][c] = Aji[(size_t)r * NROWS + c];
        }
        __syncthreads();
        #pragma unroll
        for (int r = r0; r < TT; r += 4) {
            Aij[(size_t)r * NROWS + c] = tb[c][r];
            Aji[(size_t)r * NROWS + c] = ta[c][r];
        }
    }
}

// ---------------------------------------------------------------------------
extern "C" void kernel_launch(void* const* d_in, const int* in_sizes, int n_in,
                              void* d_out, int out_size, void* d_ws, size_t ws_size,
                              hipStream_t stream)
{
    const float* x  = (const float*)d_in[0];
    const float* We = (const float*)d_in[1];
    const float* be = (const float*)d_in[2];
    const float* Wd = (const float*)d_in[3];
    const float* bd = (const float*)d_in[4];

    float* out      = (float*)d_out;
    float* recon    = out;
    float* features = out + (size_t)NROWS * D_MODEL;
    float* pre      = features + (size_t)NROWS * DICT;

    unsigned short* webf = (unsigned short*)features;                 // 128 MB
    unsigned short* xbf  = webf + (size_t)TNB * NT_K * 16384;         // + 8 MB

    long cap_l = (long)(ws_size / 4 - (size_t)NROWS * (1 + 2 * KTOP)) / NROWS;
    int cap = (int)(cap_l < 64 ? 64 : (cap_l > CAPMAX ? CAPMAX : cap_l));

    char* ws = (char*)d_ws;
    int*   ws_cand  = (int*)ws;
    int*   ws_cnt   = (int*)(ws + (size_t)NROWS * cap * 4);
    float* ws_valsT = (float*)(ws + (size_t)NROWS * (cap + 1) * 4);
    int*   ws_idxT  = (int*)(ws + (size_t)NROWS * (cap + 1 + KTOP) * 4);

    // 0) zero per-row candidate counters
    hipMemsetAsync(ws_cnt, 0, (size_t)NROWS * sizeof(int), stream);

    // 1) convert + tile + swizzle operands to bf16
    const int conv_blocks = (int)(((size_t)NROWS * 64 + (size_t)DICT * 64) / 256);
    convert_tiles<<<conv_blocks, 256, 0, stream>>>(x, We, xbf, webf);

    // 2) encoder GEMM -> approx pre_acts + fused candidate collection
    encoder_bf16<<<TMB * TNB, 512, 0, stream>>>(
        xbf, webf, be, pre, ws_cand, ws_cnt, cap);

    // 3) banded exact recompute + features zeroing + top-32 + scatter
    recompute_select_kernel<<<NROWS, 256, 0, stream>>>(
        x, We, be, pre, ws_cand, ws_cnt, cap, features, ws_valsT, ws_idxT);

    // 4) sparse decoder (coalesced transposed writes into recon region)
    decoder_kernel<<<D_MODEL, 1024, 0, stream>>>(
        Wd, bd, ws_valsT, ws_idxT, recon);

    // 5) in-place transpose reconT -> recon
    transpose_inplace<<<NTILE * (NTILE + 1) / 2, 256, 0, stream>>>(recon);
}